// Round 9
// baseline (412.466 us; speedup 1.0000x reference)
//
#include <hip/hip_runtime.h>

// Causal self-attention, B=2 T=4096 C=768 H=12 D=64, bf16 MFMA pipeline:
//   cast x -> bf16; transpose W_attn/W_proj -> [N,K] bf16
//   GEMM1 (x @ W_attn + b) -> Q[b,h,t,d], K[b,h,t,d] (pre-scaled by log2e/8),
//     V^T[b,h,d,t'] where t' is PER-64-TILE KEY-PERMUTED: key i*16+q4*4+r stored at
//     (i>>1)*32 + q4*8 + (i&1)*4 + r (feeds attention's in-register PV path).
//   GEMM mainloops: 2-phase double-buffered (R8: pushed both GEMMs below attn).
//   attention (all 16x16x32 MFMA): 512 thr / 8 waves; block p pairs q-tiles {p,63-p}
//     (waves 0-3 / 4-7), uniform 65 tile-halves/block. S^T = K.Q^T -> P lane-local;
//     pack2bf into PV B-frags; permuted V^T makes PV A-frags single conflict-free
//     16B LDS reads. P never touches LDS.
//     R9: K is NOT staged — kf frags load DIRECT from global. R8 PMC: conflicts=0
//     but LDS pipe ~85-90% busy (12.5k b128/CU, half of them K). K's [t][d] layout
//     reads coalesce into 16 lines/instr shared 4-way across quads, and the 8 waves
//     of a block + 3-4 blocks/CU (8KB tiles) hit L1 (32KB). V^T CANNOT go direct
//     (8KB/lane global stride) and stays LDS-staged (16KB dbuf). Occupancy 6->8
//     waves/SIMD (launch_bounds(512,8), VGPR~44) hides the K L1/L2 latency.
//     s_setprio(1) around the compute region (T5; multi-block CUs = role diversity).
//   GEMM2 (y @ W_proj + b) -> out fp32

#define TSEQ   4096
#define NHEAD  12
#define CDIM   768
#define C3     2304
#define BT_TOT 8192   // B*T

typedef __bf16 bf16x8 __attribute__((ext_vector_type(8)));
typedef __bf16 bf16x2 __attribute__((ext_vector_type(2)));
typedef float  f32x4  __attribute__((ext_vector_type(4)));
typedef unsigned int u32x4 __attribute__((ext_vector_type(4)));

__device__ __forceinline__ unsigned short f2bf(float f) {
  unsigned int u = __builtin_bit_cast(unsigned int, f);
  u += 0x7FFFu + ((u >> 16) & 1u);            // round-to-nearest-even
  return (unsigned short)(u >> 16);
}

// native gfx950 f32->bf16 (v_cvt_pk_bf16_f32) — 1 instr per pair
__device__ __forceinline__ unsigned int pack2bf(float a, float b) {
  bf16x2 v = {(__bf16)a, (__bf16)b};
  return __builtin_bit_cast(unsigned int, v);
}

__device__ __forceinline__ f32x4 mfma16(bf16x8 a, bf16x8 b, f32x4 c) {
  return __builtin_amdgcn_mfma_f32_16x16x32_bf16(a, b, c, 0, 0, 0);
}

typedef const __attribute__((address_space(1))) void* gas_ptr;
typedef __attribute__((address_space(3))) void* las_ptr;

// ---------------- prologue casts ----------------

__global__ __launch_bounds__(256) void cast_f32_bf16(const float* __restrict__ x,
                                                     unsigned short* __restrict__ o, int n) {
  int i = (blockIdx.x * 256 + threadIdx.x) * 4;
  if (i < n) {
    float4 v = *(const float4*)(x + i);
    ushort4 u;
    u.x = f2bf(v.x); u.y = f2bf(v.y); u.z = f2bf(v.z); u.w = f2bf(v.w);
    *(ushort4*)(o + i) = u;
  }
}

// dst[n][k] = bf16(src[k][n]);  K,N multiples of 32
__global__ __launch_bounds__(256) void transpose_cast(const float* __restrict__ src,
                                                      unsigned short* __restrict__ dst,
                                                      int K, int N) {
  __shared__ float tile[32][33];
  int n0 = blockIdx.x * 32, k0 = blockIdx.y * 32;
  int tx = threadIdx.x, ty = threadIdx.y;  // 32 x 8
#pragma unroll
  for (int i = 0; i < 4; ++i)
    tile[ty + i * 8][tx] = src[(size_t)(k0 + ty + i * 8) * N + n0 + tx];
  __syncthreads();
#pragma unroll
  for (int i = 0; i < 4; ++i)
    dst[(size_t)(n0 + ty + i * 8) * K + k0 + tx] = f2bf(tile[tx][ty + i * 8]);
}

// ---------------- GEMM core (C = A[M,K] * BT[N,K]^T), 128x128 tile, BK=32 ----------------
// 2-phase double-buffered: buf layout (shorts) cur*8192 + {A: 0..4095, B: 4096..8191}.

__device__ __forceinline__ void stage_gemm(const unsigned short* __restrict__ A,
                                           const unsigned short* __restrict__ BTm,
                                           int K, int m0, int n0, int k0,
                                           unsigned short* buf, int wave,
                                           int srow, int scol) {
#pragma unroll
  for (int r = 0; r < 2; ++r) {
    const unsigned short* ga = A + (size_t)(m0 + r * 64 + srow) * K + k0 + scol;
    __builtin_amdgcn_global_load_lds((gas_ptr)ga,
        (las_ptr)(buf + r * 2048 + wave * 512), 16, 0, 0);
    const unsigned short* gb = BTm + (size_t)(n0 + r * 64 + srow) * K + k0 + scol;
    __builtin_amdgcn_global_load_lds((gas_ptr)gb,
        (las_ptr)(buf + 4096 + r * 2048 + wave * 512), 16, 0, 0);
  }
}

__device__ __forceinline__ void gemm_bt_mainloop(const unsigned short* __restrict__ A,
                                                 const unsigned short* __restrict__ BTm,
                                                 int K, int m0, int n0,
                                                 unsigned short* lds, f32x4 acc[4][4]) {
  const int tid = threadIdx.x;
  const int wave = tid >> 6, lane = tid & 63;
  const int quad = lane >> 4, l16 = lane & 15;
  const int wm = (wave >> 1) * 64, wn = (wave & 1) * 64;
  const int srow = tid >> 2;          // 0..63
  const int scol = (tid & 3) * 8;     // shorts

  stage_gemm(A, BTm, K, m0, n0, 0, lds, wave, srow, scol);
  __syncthreads();                    // prologue stage visible

  int cur = 0;
  for (int k0 = 0; k0 < K; k0 += 32) {
    if (k0 + 32 < K)                  // issue next-tile loads FIRST (overlap with MFMA)
      stage_gemm(A, BTm, K, m0, n0, k0 + 32, lds + (cur ^ 1) * 8192, wave, srow, scol);

    const unsigned short* buf = lds + cur * 8192;
    bf16x8 af[4], bfr[4];
#pragma unroll
    for (int i = 0; i < 4; ++i) {
      af[i]  = *(const bf16x8*)(buf + (wm + i * 16 + l16) * 32 + quad * 8);
      bfr[i] = *(const bf16x8*)(buf + 4096 + (wn + i * 16 + l16) * 32 + quad * 8);
    }
#pragma unroll
    for (int i = 0; i < 4; ++i)
#pragma unroll
      for (int j = 0; j < 4; ++j)
        acc[i][j] = mfma16(af[i], bfr[j], acc[i][j]);

    __syncthreads();   // single barrier: drains stage(t+1) (vmcnt) + my ds_reads (lgkm)
    cur ^= 1;
  }
}

// GEMM1: qkv = x@W_attn + b_attn -> Q/K (b,h,t,d) and key-permuted V^T (b,h,d,t'), bf16.
// K pre-scaled by log2e/8. Epilogue: tile -> LDS (transposed for V), then coalesced
// 16B stores; the V path gathers 2x8B per 16B chunk to apply the per-64 key permutation
// col'(key) = (key>>5)*32 + ((key>>2)&3)*8 + ((key>>4)&1)*4 + (key&3).
__global__ __launch_bounds__(256, 4) void gemm_qkv_kernel(
    const unsigned short* __restrict__ A, const unsigned short* __restrict__ BTm,
    const float* __restrict__ bias,
    unsigned short* __restrict__ qbuf, unsigned short* __restrict__ kbuf,
    unsigned short* __restrict__ vtbuf) {
  __shared__ __align__(16) unsigned short lds[128 * 136];  // mainloop dbuf uses first 16384
  f32x4 zero = {0.f, 0.f, 0.f, 0.f};
  f32x4 acc[4][4];
#pragma unroll
  for (int i = 0; i < 4; ++i)
#pragma unroll
    for (int j = 0; j < 4; ++j) acc[i][j] = zero;

  const int m0 = blockIdx.y * 128, n0 = blockIdx.x * 128;
  gemm_bt_mainloop(A, BTm, CDIM, m0, n0, lds, acc);
  // mainloop's final barrier: all waves synced, all LDS reads drained -> safe to reuse

  const int tid = threadIdx.x;
  const int wave = tid >> 6, lane = tid & 63;
  const int quad = lane >> 4, l16 = lane & 15;
  const int wm = (wave >> 1) * 64, wn = (wave & 1) * 64;
  const float KSCALE = 0.125f * 1.44269504088896340736f;  // 1/sqrt(64) * log2(e)

  const int seg = n0 / CDIM;   // 0=Q 1=K 2=V — uniform per block (128 | 768)
  const float mult = (seg == 1) ? KSCALE : 1.0f;

#pragma unroll
  for (int j = 0; j < 4; ++j) {
    const int nl = wn + j * 16 + l16;
    const float bv = bias[n0 + nl];
#pragma unroll
    for (int i = 0; i < 4; ++i) {
#pragma unroll
      for (int r = 0; r < 4; ++r) {
        const int ml = wm + i * 16 + quad * 4 + r;
        unsigned short val = f2bf((acc[i][j][r] + bv) * mult);
        if (seg < 2) lds[ml * 136 + nl] = val;   // [t][n] for Q/K
        else         lds[nl * 136 + ml] = val;   // [n][t] for V^T
      }
    }
  }
  __syncthreads();

  const int row = tid >> 1, half = tid & 1;
  const unsigned short* src = lds + row * 136 + half * 64;
  if (seg < 2) {
    const int m = m0 + row, b = m >> 12, t = m & (TSEQ - 1);
    const int nn = (n0 - seg * CDIM) + half * 64;   // multiple of 64
    const int h = nn >> 6;
    unsigned short* base = (seg == 0) ? qbuf : kbuf;
    unsigned short* dst = base + ((size_t)(b * NHEAD + h) * TSEQ + t) * 64;
#pragma unroll
    for (int k = 0; k < 8; ++k)
      *(uint4*)(dst + k * 8) = *(const uint4*)(src + k * 8);
  } else {
    const int nn = (n0 - 2 * CDIM) + row;
    const int h = nn >> 6, d = nn & 63;
    const int b = m0 >> 12, t0 = (m0 & (TSEQ - 1)) + half * 64;
    unsigned short* dst = vtbuf + ((size_t)(b * NHEAD + h) * 64 + d) * TSEQ + t0;
    // permuted store: dst chunk k holds keys {2(k>>2)}*16+(k&3)*4+0..3 then +16
#pragma unroll
    for (int k = 0; k < 8; ++k) {
      const int s0 = 32 * (k >> 2) + 4 * (k & 3);
      uint2 a = *(const uint2*)(src + s0);
      uint2 c = *(const uint2*)(src + s0 + 16);
      uint4 w = {a.x, a.y, c.x, c.y};
      *(uint4*)(dst + k * 8) = w;
    }
  }
}

// GEMM2: out = y@W_proj + b_proj (fp32 out)
__global__ __launch_bounds__(256, 4) void gemm_out_kernel(
    const unsigned short* __restrict__ A, const unsigned short* __restrict__ BTm,
    const float* __restrict__ bias, float* __restrict__ out) {
  __shared__ __align__(16) unsigned short lds[16384];   // 2-phase dbuf
  f32x4 zero = {0.f, 0.f, 0.f, 0.f};
  f32x4 acc[4][4];
#pragma unroll
  for (int i = 0; i < 4; ++i)
#pragma unroll
    for (int j = 0; j < 4; ++j) acc[i][j] = zero;

  const int m0 = blockIdx.y * 128, n0 = blockIdx.x * 128;
  gemm_bt_mainloop(A, BTm, CDIM, m0, n0, lds, acc);

  const int tid = threadIdx.x;
  const int wave = tid >> 6, lane = tid & 63;
  const int quad = lane >> 4, l16 = lane & 15;
  const int wm = (wave >> 1) * 64, wn = (wave & 1) * 64;

#pragma unroll
  for (int j = 0; j < 4; ++j) {
    int n = n0 + wn + j * 16 + l16;
    float bv = bias[n];
#pragma unroll
    for (int i = 0; i < 4; ++i) {
#pragma unroll
      for (int r = 0; r < 4; ++r) {
        int m = m0 + wm + i * 16 + quad * 4 + r;
        out[(size_t)m * CDIM + n] = acc[i][j][r] + bv;
      }
    }
  }
}

// ---------------- attention ----------------
// S^T: A=K (m=key=l16 within 16-group, k=d=quad*8+j), B=Q (n=q=l16).
// C: col=l16=q, row=quad*4+r=key -> P lane-local (16 values: keys 16i+quad*4+r).
// PV (16x16x32): A = permuted V^T from LDS — ONE 16B read per frag (k-slot quad*8+i*4+r
// carries key 16(2f+i)+quad*4+r, f=frag); B = pack2bf(s-regs) in matching order.
// O C: col=l16=q, row=quad*4+r=d (+16dt) -> per-row norm via quad shfl-reduce.
// K frags load DIRECT from global (L1/L2-served; no LDS, no swizzle).

// 512 threads stage one 64x64 (permuted) V^T tile (16B/lane).
__device__ __forceinline__ void stage_v(const unsigned short* __restrict__ Vp,
                                        int j0, unsigned short* vb,
                                        int tid, int wave) {
  const int row = tid >> 3;                              // 0..63
  const int col = ((tid & 7) ^ (row & 7)) * 8;           // XOR swizzle (self-inverse)
  __builtin_amdgcn_global_load_lds((gas_ptr)(Vp + (size_t)row * TSEQ + j0 + col),
                                   (las_ptr)(vb + wave * 512), 16, 0, 0);
}

__device__ __forceinline__ void qk_score(const bf16x8 kf[8], const bf16x8 qf[2], f32x4 s[4]) {
  f32x4 zero = {0.f, 0.f, 0.f, 0.f};
#pragma unroll
  for (int i = 0; i < 4; ++i)
    s[i] = mfma16(kf[2 * i + 1], qf[1], mfma16(kf[2 * i], qf[0], zero));
}

// exp2 + (diagonal) causal mask + lane-local partial row-sum; packs P into the two
// PV B-frags (k-slot order quad*8 + i*4 + r == permuted V^T storage order).
template <bool MASKED>
__device__ __forceinline__ void exp_pack(const f32x4 s[4], int j0, int qabs,
                                         int l16, int quad, float& lsum, bf16x8 pf[2]) {
  unsigned int w[8];
#pragma unroll
  for (int i = 0; i < 4; ++i) {
    float p[4];
#pragma unroll
    for (int r = 0; r < 4; ++r) {
      p[r] = __builtin_amdgcn_exp2f(s[i][r]);
      if (MASKED) {
        if (j0 + i * 16 + quad * 4 + r > qabs) p[r] = 0.f;
      }
      lsum += p[r];
    }
    w[2 * i]     = pack2bf(p[0], p[1]);
    w[2 * i + 1] = pack2bf(p[2], p[3]);
  }
  u32x4 lo = {w[0], w[1], w[2], w[3]};   // keys i=0,1 at k-slots quad*8 + 0..7
  u32x4 hi = {w[4], w[5], w[6], w[7]};   // keys i=2,3
  pf[0] = __builtin_bit_cast(bf16x8, lo);
  pf[1] = __builtin_bit_cast(bf16x8, hi);
}

// PV: 8 mfma16 off 8 conflict-free 16B v reads (frag0 block=quad, frag1 block=4+quad,
// de-swizzled by x7 = l16&7; rows d = dt*16+l16).
__device__ __forceinline__ void pv(const unsigned short* __restrict__ vb,
                                   int l16, int quad, int x7,
                                   const bf16x8 pf[2], f32x4 o[4]) {
#pragma unroll
  for (int dt = 0; dt < 4; ++dt) {
    const unsigned short* vr = vb + (dt * 16 + l16) * 64;
    bf16x8 v0 = *(const bf16x8*)(vr + ((quad ^ x7) * 8));
    bf16x8 v1 = *(const bf16x8*)(vr + (((4 + quad) ^ x7) * 8));
    o[dt] = mfma16(v1, pf[1], mfma16(v0, pf[0], o[dt]));
  }
}

__global__ __launch_bounds__(512, 8) void attn_kernel(const unsigned short* __restrict__ qbuf,
                                                      const unsigned short* __restrict__ kbuf,
                                                      const unsigned short* __restrict__ vtbuf,
                                                      unsigned short* __restrict__ y) {
  __shared__ __align__(16) unsigned short v_lds[2][64 * 64];      // 2 x 8KB (V only)

  const int tid = threadIdx.x;
  const int wave = tid >> 6, lane = tid & 63;
  const int quad = lane >> 4, l16 = lane & 15;
  const int x7 = l16 & 7;

  const int bh = blockIdx.x % 24;
  const int p = blockIdx.x / 24;            // 0..31; p=0 (longest stream) dispatches first
  const bool isA = wave < 4;                // waves 0-3: q-tile p; waves 4-7: q-tile 63-p
  const int qtile = isA ? p : (63 - p);
  const int q0 = qtile * 64 + (wave & 3) * 16;

  const unsigned short* Qp = qbuf + (size_t)bh * TSEQ * 64;
  const unsigned short* Kp = kbuf + (size_t)bh * TSEQ * 64;
  const unsigned short* Vp = vtbuf + (size_t)bh * 64 * TSEQ;

  bf16x8 qf[2];
  qf[0] = *(const bf16x8*)(Qp + (size_t)(q0 + l16) * 64 + quad * 8);
  qf[1] = *(const bf16x8*)(Qp + (size_t)(q0 + l16) * 64 + 32 + quad * 8);

  f32x4 zero = {0.f, 0.f, 0.f, 0.f};
  f32x4 o[4];
#pragma unroll
  for (int dt = 0; dt < 4; ++dt) o[dt] = zero;
  float ls = 0.f;

  const int ntiles = 64 - p;                  // key tiles 0..63-p
  const int lasttile = isA ? p : (ntiles - 1);// this wave's diagonal tile (== qtile)

  // per-lane K fragment base (shorts): rows advance 16/frag-pair, tiles advance 64*64
  const unsigned short* Kl = Kp + (size_t)l16 * 64 + quad * 8;

  stage_v(Vp, 0, v_lds[0], tid, wave);

  for (int jt = 0; jt < ntiles; ++jt) {
    __syncthreads();   // stage(jt) visible; other buffer free for restage
    if (jt + 1 < ntiles)
      stage_v(Vp, (jt + 1) * 64, v_lds[(jt + 1) & 1], tid, wave);

    if (jt <= lasttile) {                    // wave-uniform; B-waves always active
      const unsigned short* vb = v_lds[jt & 1];
      const int j0 = jt * 64;

      // kf DIRECT from global: key = j0 + 16i + l16, d-block = quad*8 (+32)
      const unsigned short* Kt = Kl + (size_t)j0 * 64;
      bf16x8 kf[8];
#pragma unroll
      for (int i = 0; i < 4; ++i) {
        kf[2 * i]     = *(const bf16x8*)(Kt + (size_t)(16 * i) * 64);
        kf[2 * i + 1] = *(const bf16x8*)(Kt + (size_t)(16 * i) * 64 + 32);
      }

      __builtin_amdgcn_s_setprio(1);
      f32x4 s[4];
      qk_score(kf, qf, s);

      bf16x8 pf[2];
      if (jt == lasttile) exp_pack<true>(s, j0, q0 + l16, l16, quad, ls, pf);
      else                exp_pack<false>(s, j0, q0 + l16, l16, quad, ls, pf);

      pv(vb, l16, quad, x7, pf, o);
      __builtin_amdgcn_s_setprio(0);
    }
  }

  // full row-sum for q=l16: reduce partial sums across the 4 quads
  ls += __shfl_xor(ls, 16); ls += __shfl_xor(ls, 32);
  const float inv = 1.0f / ls;

  // O: col=l16=q (t = q0+l16), row = dt*16 + quad*4 + r = d
  const int b = bh / NHEAD, hd = bh - b * NHEAD;
  unsigned short* yr = y + (size_t)(b * TSEQ + q0 + l16) * CDIM + hd * 64 + quad * 4;
#pragma unroll
  for (int dt = 0; dt < 4; ++dt) {
    uint2 w;
    w.x = pack2bf(o[dt][0] * inv, o[dt][1] * inv);
    w.y = pack2bf(o[dt][2] * inv, o[dt][3] * inv);
    *(uint2*)(yr + dt * 16) = w;
  }
}

// ---------------- launch ----------------

extern "C" void kernel_launch(void* const* d_in, const int* in_sizes, int n_in,
                              void* d_out, int out_size, void* d_ws, size_t ws_size,
                              hipStream_t stream) {
  const float* x      = (const float*)d_in[0];
  const float* W_attn = (const float*)d_in[1];
  const float* b_attn = (const float*)d_in[2];
  const float* W_proj = (const float*)d_in[3];
  const float* b_proj = (const float*)d_in[4];
  float* out = (float*)d_out;

  unsigned short* xb    = (unsigned short*)d_ws;                  // [8192,768] bf16 (later reused as y)
  unsigned short* WaT   = xb + (size_t)BT_TOT * CDIM;             // [2304,768]
  unsigned short* WpT   = WaT + (size_t)C3 * CDIM;                // [768,768]
  unsigned short* qbuf  = WpT + (size_t)CDIM * CDIM;              // [24,4096,64]
  unsigned short* kbuf  = qbuf + (size_t)2 * NHEAD * TSEQ * 64;   // [24,4096,64]
  unsigned short* vtbuf = kbuf + (size_t)2 * NHEAD * TSEQ * 64;   // [24,64,4096] (key-permuted)
  unsigned short* ybuf  = xb;  // x dead after GEMM1

  cast_f32_bf16<<<(BT_TOT * CDIM) / 1024, 256, 0, stream>>>(x, xb, BT_TOT * CDIM);
  transpose_cast<<<dim3(C3 / 32, CDIM / 32), dim3(32, 8), 0, stream>>>(W_attn, WaT, CDIM, C3);
  transpose_cast<<<dim3(CDIM / 32, CDIM / 32), dim3(32, 8), 0, stream>>>(W_proj, WpT, CDIM, CDIM);

  gemm_qkv_kernel<<<dim3(C3 / 128, BT_TOT / 128), 256, 0, stream>>>(xb, WaT, b_attn,
                                                                    qbuf, kbuf, vtbuf);
  attn_kernel<<<dim3(24 * 32), 512, 0, stream>>>(qbuf, kbuf, vtbuf, ybuf);
  gemm_out_kernel<<<dim3(CDIM / 128, BT_TOT / 128), 256, 0, stream>>>(ybuf, WpT, b_proj, out);
}

// Round 10
// 228.133 us; speedup vs baseline: 1.8080x; 1.8080x over previous
//
#include <hip/hip_runtime.h>

// Causal self-attention, B=2 T=4096 C=768 H=12 D=64, bf16 MFMA pipeline:
//   cast x -> bf16; transpose W_attn/W_proj -> [N,K] bf16
//   GEMM1 (x @ W_attn + b) -> Q[b,h,t,d], K[b,h,t,d] (pre-scaled by log2e/8),
//     V^T[b,h,d,t'] where t' is PER-64-TILE KEY-PERMUTED: key i*16+q4*4+r stored at
//     (i>>1)*32 + q4*8 + (i&1)*4 + r (feeds attention's in-register PV path).
//   GEMM mainloops: 2-phase double-buffered (R8).
//   attention (all 16x16x32 MFMA): 256 thr / 4 waves; block p pairs q-tiles {p,63-p}
//     (waves 0-1 / 2-3). Each wave owns 32 q-rows as TWO 16-row chunks sharing one
//     kf[8]+v[8] fragment load -> 8 b128/chunk vs R8's 16 (R8 PMC: conflicts=0 but
//     LDS pipe ~85-90% busy = the wall). R2's same geometry failed only because of
//     the P-LDS round-trip chain, which R6's in-register P removed; v reads have no
//     softmax dependence so the chain is short. K stays LDS-staged (R9's direct-K
//     thrashed L1/L2: MfmaUtil 7.7%, WRITE_SIZE 8x from broken write-combining).
//     S^T = K.Q^T -> P lane-local; pack2bf into PV B-frags; permuted V^T makes PV
//     A-frags single conflict-free 16B LDS reads. P never touches LDS.
//   GEMM2 (y @ W_proj + b) -> out fp32

#define TSEQ   4096
#define NHEAD  12
#define CDIM   768
#define C3     2304
#define BT_TOT 8192   // B*T

typedef __bf16 bf16x8 __attribute__((ext_vector_type(8)));
typedef __bf16 bf16x2 __attribute__((ext_vector_type(2)));
typedef float  f32x4  __attribute__((ext_vector_type(4)));
typedef unsigned int u32x4 __attribute__((ext_vector_type(4)));

__device__ __forceinline__ unsigned short f2bf(float f) {
  unsigned int u = __builtin_bit_cast(unsigned int, f);
  u += 0x7FFFu + ((u >> 16) & 1u);            // round-to-nearest-even
  return (unsigned short)(u >> 16);
}

// native gfx950 f32->bf16 (v_cvt_pk_bf16_f32) — 1 instr per pair
__device__ __forceinline__ unsigned int pack2bf(float a, float b) {
  bf16x2 v = {(__bf16)a, (__bf16)b};
  return __builtin_bit_cast(unsigned int, v);
}

__device__ __forceinline__ f32x4 mfma16(bf16x8 a, bf16x8 b, f32x4 c) {
  return __builtin_amdgcn_mfma_f32_16x16x32_bf16(a, b, c, 0, 0, 0);
}

typedef const __attribute__((address_space(1))) void* gas_ptr;
typedef __attribute__((address_space(3))) void* las_ptr;

// ---------------- prologue casts ----------------

__global__ __launch_bounds__(256) void cast_f32_bf16(const float* __restrict__ x,
                                                     unsigned short* __restrict__ o, int n) {
  int i = (blockIdx.x * 256 + threadIdx.x) * 4;
  if (i < n) {
    float4 v = *(const float4*)(x + i);
    ushort4 u;
    u.x = f2bf(v.x); u.y = f2bf(v.y); u.z = f2bf(v.z); u.w = f2bf(v.w);
    *(ushort4*)(o + i) = u;
  }
}

// dst[n][k] = bf16(src[k][n]);  K,N multiples of 32
__global__ __launch_bounds__(256) void transpose_cast(const float* __restrict__ src,
                                                      unsigned short* __restrict__ dst,
                                                      int K, int N) {
  __shared__ float tile[32][33];
  int n0 = blockIdx.x * 32, k0 = blockIdx.y * 32;
  int tx = threadIdx.x, ty = threadIdx.y;  // 32 x 8
#pragma unroll
  for (int i = 0; i < 4; ++i)
    tile[ty + i * 8][tx] = src[(size_t)(k0 + ty + i * 8) * N + n0 + tx];
  __syncthreads();
#pragma unroll
  for (int i = 0; i < 4; ++i)
    dst[(size_t)(n0 + ty + i * 8) * K + k0 + tx] = f2bf(tile[tx][ty + i * 8]);
}

// ---------------- GEMM core (C = A[M,K] * BT[N,K]^T), 128x128 tile, BK=32 ----------------
// 2-phase double-buffered: buf layout (shorts) cur*8192 + {A: 0..4095, B: 4096..8191}.

__device__ __forceinline__ void stage_gemm(const unsigned short* __restrict__ A,
                                           const unsigned short* __restrict__ BTm,
                                           int K, int m0, int n0, int k0,
                                           unsigned short* buf, int wave,
                                           int srow, int scol) {
#pragma unroll
  for (int r = 0; r < 2; ++r) {
    const unsigned short* ga = A + (size_t)(m0 + r * 64 + srow) * K + k0 + scol;
    __builtin_amdgcn_global_load_lds((gas_ptr)ga,
        (las_ptr)(buf + r * 2048 + wave * 512), 16, 0, 0);
    const unsigned short* gb = BTm + (size_t)(n0 + r * 64 + srow) * K + k0 + scol;
    __builtin_amdgcn_global_load_lds((gas_ptr)gb,
        (las_ptr)(buf + 4096 + r * 2048 + wave * 512), 16, 0, 0);
  }
}

__device__ __forceinline__ void gemm_bt_mainloop(const unsigned short* __restrict__ A,
                                                 const unsigned short* __restrict__ BTm,
                                                 int K, int m0, int n0,
                                                 unsigned short* lds, f32x4 acc[4][4]) {
  const int tid = threadIdx.x;
  const int wave = tid >> 6, lane = tid & 63;
  const int quad = lane >> 4, l16 = lane & 15;
  const int wm = (wave >> 1) * 64, wn = (wave & 1) * 64;
  const int srow = tid >> 2;          // 0..63
  const int scol = (tid & 3) * 8;     // shorts

  stage_gemm(A, BTm, K, m0, n0, 0, lds, wave, srow, scol);
  __syncthreads();                    // prologue stage visible

  int cur = 0;
  for (int k0 = 0; k0 < K; k0 += 32) {
    if (k0 + 32 < K)                  // issue next-tile loads FIRST (overlap with MFMA)
      stage_gemm(A, BTm, K, m0, n0, k0 + 32, lds + (cur ^ 1) * 8192, wave, srow, scol);

    const unsigned short* buf = lds + cur * 8192;
    bf16x8 af[4], bfr[4];
#pragma unroll
    for (int i = 0; i < 4; ++i) {
      af[i]  = *(const bf16x8*)(buf + (wm + i * 16 + l16) * 32 + quad * 8);
      bfr[i] = *(const bf16x8*)(buf + 4096 + (wn + i * 16 + l16) * 32 + quad * 8);
    }
#pragma unroll
    for (int i = 0; i < 4; ++i)
#pragma unroll
      for (int j = 0; j < 4; ++j)
        acc[i][j] = mfma16(af[i], bfr[j], acc[i][j]);

    __syncthreads();   // single barrier: drains stage(t+1) (vmcnt) + my ds_reads (lgkm)
    cur ^= 1;
  }
}

// GEMM1: qkv = x@W_attn + b_attn -> Q/K (b,h,t,d) and key-permuted V^T (b,h,d,t'), bf16.
// K pre-scaled by log2e/8. Epilogue: tile -> LDS (transposed for V), then coalesced
// 16B stores; the V path gathers 2x8B per 16B chunk to apply the per-64 key permutation
// col'(key) = (key>>5)*32 + ((key>>2)&3)*8 + ((key>>4)&1)*4 + (key&3).
__global__ __launch_bounds__(256, 4) void gemm_qkv_kernel(
    const unsigned short* __restrict__ A, const unsigned short* __restrict__ BTm,
    const float* __restrict__ bias,
    unsigned short* __restrict__ qbuf, unsigned short* __restrict__ kbuf,
    unsigned short* __restrict__ vtbuf) {
  __shared__ __align__(16) unsigned short lds[128 * 136];  // mainloop dbuf uses first 16384
  f32x4 zero = {0.f, 0.f, 0.f, 0.f};
  f32x4 acc[4][4];
#pragma unroll
  for (int i = 0; i < 4; ++i)
#pragma unroll
    for (int j = 0; j < 4; ++j) acc[i][j] = zero;

  const int m0 = blockIdx.y * 128, n0 = blockIdx.x * 128;
  gemm_bt_mainloop(A, BTm, CDIM, m0, n0, lds, acc);
  // mainloop's final barrier: all waves synced, all LDS reads drained -> safe to reuse

  const int tid = threadIdx.x;
  const int wave = tid >> 6, lane = tid & 63;
  const int quad = lane >> 4, l16 = lane & 15;
  const int wm = (wave >> 1) * 64, wn = (wave & 1) * 64;
  const float KSCALE = 0.125f * 1.44269504088896340736f;  // 1/sqrt(64) * log2(e)

  const int seg = n0 / CDIM;   // 0=Q 1=K 2=V — uniform per block (128 | 768)
  const float mult = (seg == 1) ? KSCALE : 1.0f;

#pragma unroll
  for (int j = 0; j < 4; ++j) {
    const int nl = wn + j * 16 + l16;
    const float bv = bias[n0 + nl];
#pragma unroll
    for (int i = 0; i < 4; ++i) {
#pragma unroll
      for (int r = 0; r < 4; ++r) {
        const int ml = wm + i * 16 + quad * 4 + r;
        unsigned short val = f2bf((acc[i][j][r] + bv) * mult);
        if (seg < 2) lds[ml * 136 + nl] = val;   // [t][n] for Q/K
        else         lds[nl * 136 + ml] = val;   // [n][t] for V^T
      }
    }
  }
  __syncthreads();

  const int row = tid >> 1, half = tid & 1;
  const unsigned short* src = lds + row * 136 + half * 64;
  if (seg < 2) {
    const int m = m0 + row, b = m >> 12, t = m & (TSEQ - 1);
    const int nn = (n0 - seg * CDIM) + half * 64;   // multiple of 64
    const int h = nn >> 6;
    unsigned short* base = (seg == 0) ? qbuf : kbuf;
    unsigned short* dst = base + ((size_t)(b * NHEAD + h) * TSEQ + t) * 64;
#pragma unroll
    for (int k = 0; k < 8; ++k)
      *(uint4*)(dst + k * 8) = *(const uint4*)(src + k * 8);
  } else {
    const int nn = (n0 - 2 * CDIM) + row;
    const int h = nn >> 6, d = nn & 63;
    const int b = m0 >> 12, t0 = (m0 & (TSEQ - 1)) + half * 64;
    unsigned short* dst = vtbuf + ((size_t)(b * NHEAD + h) * 64 + d) * TSEQ + t0;
    // permuted store: dst chunk k holds keys {2(k>>2)}*16+(k&3)*4+0..3 then +16
#pragma unroll
    for (int k = 0; k < 8; ++k) {
      const int s0 = 32 * (k >> 2) + 4 * (k & 3);
      uint2 a = *(const uint2*)(src + s0);
      uint2 c = *(const uint2*)(src + s0 + 16);
      uint4 w = {a.x, a.y, c.x, c.y};
      *(uint4*)(dst + k * 8) = w;
    }
  }
}

// GEMM2: out = y@W_proj + b_proj (fp32 out)
__global__ __launch_bounds__(256, 4) void gemm_out_kernel(
    const unsigned short* __restrict__ A, const unsigned short* __restrict__ BTm,
    const float* __restrict__ bias, float* __restrict__ out) {
  __shared__ __align__(16) unsigned short lds[16384];   // 2-phase dbuf
  f32x4 zero = {0.f, 0.f, 0.f, 0.f};
  f32x4 acc[4][4];
#pragma unroll
  for (int i = 0; i < 4; ++i)
#pragma unroll
    for (int j = 0; j < 4; ++j) acc[i][j] = zero;

  const int m0 = blockIdx.y * 128, n0 = blockIdx.x * 128;
  gemm_bt_mainloop(A, BTm, CDIM, m0, n0, lds, acc);

  const int tid = threadIdx.x;
  const int wave = tid >> 6, lane = tid & 63;
  const int quad = lane >> 4, l16 = lane & 15;
  const int wm = (wave >> 1) * 64, wn = (wave & 1) * 64;

#pragma unroll
  for (int j = 0; j < 4; ++j) {
    int n = n0 + wn + j * 16 + l16;
    float bv = bias[n];
#pragma unroll
    for (int i = 0; i < 4; ++i) {
#pragma unroll
      for (int r = 0; r < 4; ++r) {
        int m = m0 + wm + i * 16 + quad * 4 + r;
        out[(size_t)m * CDIM + n] = acc[i][j][r] + bv;
      }
    }
  }
}

// ---------------- attention ----------------
// S^T: A=K (m=key=l16 within 16-group, k=d=quad*8+j), B=Q (n=q=l16).
// C: col=l16=q, row=quad*4+r=key -> P lane-local (16 values: keys 16i+quad*4+r).
// PV (16x16x32): A = permuted V^T from LDS — ONE 16B read per frag (k-slot quad*8+i*4+r
// carries key 16(2f+i)+quad*4+r, f=frag); B = pack2bf(s-regs) in matching order.
// O C: col=l16=q, row=quad*4+r=d (+16dt) -> per-row norm via quad shfl-reduce.
// DUAL CHUNK: each wave computes chunks q0 and q0+16 off ONE kf/v fragment set.

// 256 threads stage one 64x64 K tile + one 64x64 (permuted) V^T tile (2x16B/lane each).
__device__ __forceinline__ void stage_kv4(const unsigned short* __restrict__ Kp,
                                          const unsigned short* __restrict__ Vp,
                                          int j0, unsigned short* kb, unsigned short* vb,
                                          int tid, int wave) {
  const int row = tid >> 3;                              // 0..31
  const int col = ((tid & 7) ^ (row & 7)) * 8;           // swizzle: (row+32)&7 == row&7
  __builtin_amdgcn_global_load_lds((gas_ptr)(Kp + (size_t)(j0 + row) * 64 + col),
                                   (las_ptr)(kb + wave * 512), 16, 0, 0);
  __builtin_amdgcn_global_load_lds((gas_ptr)(Kp + (size_t)(j0 + 32 + row) * 64 + col),
                                   (las_ptr)(kb + 2048 + wave * 512), 16, 0, 0);
  __builtin_amdgcn_global_load_lds((gas_ptr)(Vp + (size_t)row * TSEQ + j0 + col),
                                   (las_ptr)(vb + wave * 512), 16, 0, 0);
  __builtin_amdgcn_global_load_lds((gas_ptr)(Vp + (size_t)(row + 32) * TSEQ + j0 + col),
                                   (las_ptr)(vb + 2048 + wave * 512), 16, 0, 0);
}

__device__ __forceinline__ void qk_score(const bf16x8 kf[8], const bf16x8 qf[2], f32x4 s[4]) {
  f32x4 zero = {0.f, 0.f, 0.f, 0.f};
#pragma unroll
  for (int i = 0; i < 4; ++i)
    s[i] = mfma16(kf[2 * i + 1], qf[1], mfma16(kf[2 * i], qf[0], zero));
}

// exp2 + (diagonal) causal mask + lane-local partial row-sum; packs P into the two
// PV B-frags (k-slot order quad*8 + i*4 + r == permuted V^T storage order).
template <bool MASKED>
__device__ __forceinline__ void exp_pack(const f32x4 s[4], int j0, int qabs,
                                         int l16, int quad, float& lsum, bf16x8 pf[2]) {
  unsigned int w[8];
#pragma unroll
  for (int i = 0; i < 4; ++i) {
    float p[4];
#pragma unroll
    for (int r = 0; r < 4; ++r) {
      p[r] = __builtin_amdgcn_exp2f(s[i][r]);
      if (MASKED) {
        if (j0 + i * 16 + quad * 4 + r > qabs) p[r] = 0.f;
      }
      lsum += p[r];
    }
    w[2 * i]     = pack2bf(p[0], p[1]);
    w[2 * i + 1] = pack2bf(p[2], p[3]);
  }
  u32x4 lo = {w[0], w[1], w[2], w[3]};   // keys i=0,1 at k-slots quad*8 + 0..7
  u32x4 hi = {w[4], w[5], w[6], w[7]};   // keys i=2,3
  pf[0] = __builtin_bit_cast(bf16x8, lo);
  pf[1] = __builtin_bit_cast(bf16x8, hi);
}

// PV for BOTH chunks off one set of 8 conflict-free 16B v reads.
__device__ __forceinline__ void pv_dual(const unsigned short* __restrict__ vb,
                                        int l16, int quad, int x7,
                                        const bf16x8 pf0[2], const bf16x8 pf1[2],
                                        f32x4 o0[4], f32x4 o1[4]) {
#pragma unroll
  for (int dt = 0; dt < 4; ++dt) {
    const unsigned short* vr = vb + (dt * 16 + l16) * 64;
    bf16x8 v0 = *(const bf16x8*)(vr + ((quad ^ x7) * 8));
    bf16x8 v1 = *(const bf16x8*)(vr + (((4 + quad) ^ x7) * 8));
    o0[dt] = mfma16(v1, pf0[1], mfma16(v0, pf0[0], o0[dt]));
    o1[dt] = mfma16(v1, pf1[1], mfma16(v0, pf1[0], o1[dt]));
  }
}

__global__ __launch_bounds__(256, 3) void attn_kernel(const unsigned short* __restrict__ qbuf,
                                                      const unsigned short* __restrict__ kbuf,
                                                      const unsigned short* __restrict__ vtbuf,
                                                      unsigned short* __restrict__ y) {
  __shared__ __align__(16) unsigned short k_lds[2][64 * 64];      // 2 x 8KB
  __shared__ __align__(16) unsigned short v_lds[2][64 * 64];      // 2 x 8KB

  const int tid = threadIdx.x;
  const int wave = tid >> 6, lane = tid & 63;
  const int quad = lane >> 4, l16 = lane & 15;
  const int x7 = l16 & 7;

  const int bh = blockIdx.x % 24;
  const int p = blockIdx.x / 24;            // 0..31; p=0 (longest stream) dispatches first
  const bool isA = wave < 2;                // waves 0-1: q-tile p; waves 2-3: q-tile 63-p
  const int qtile = isA ? p : (63 - p);
  const int q0 = qtile * 64 + (wave & 1) * 32;   // this wave's 32-row base (2 chunks)

  const unsigned short* Qp = qbuf + (size_t)bh * TSEQ * 64;
  const unsigned short* Kp = kbuf + (size_t)bh * TSEQ * 64;
  const unsigned short* Vp = vtbuf + (size_t)bh * 64 * TSEQ;

  bf16x8 qf0[2], qf1[2];
  qf0[0] = *(const bf16x8*)(Qp + (size_t)(q0 + l16) * 64 + quad * 8);
  qf0[1] = *(const bf16x8*)(Qp + (size_t)(q0 + l16) * 64 + 32 + quad * 8);
  qf1[0] = *(const bf16x8*)(Qp + (size_t)(q0 + 16 + l16) * 64 + quad * 8);
  qf1[1] = *(const bf16x8*)(Qp + (size_t)(q0 + 16 + l16) * 64 + 32 + quad * 8);

  f32x4 zero = {0.f, 0.f, 0.f, 0.f};
  f32x4 o0[4], o1[4];
#pragma unroll
  for (int dt = 0; dt < 4; ++dt) { o0[dt] = zero; o1[dt] = zero; }
  float ls0 = 0.f, ls1 = 0.f;

  const int kcol0 = (quad ^ x7) * 8;          // swizzled K frag column (shorts)
  const int ntiles = 64 - p;                  // key tiles 0..63-p
  const int lasttile = isA ? p : (ntiles - 1);// this wave's diagonal tile (== qtile)

  stage_kv4(Kp, Vp, 0, k_lds[0], v_lds[0], tid, wave);

  for (int jt = 0; jt < ntiles; ++jt) {
    __syncthreads();   // stage(jt) visible; other buffer free for restage
    if (jt + 1 < ntiles)
      stage_kv4(Kp, Vp, (jt + 1) * 64, k_lds[(jt + 1) & 1], v_lds[(jt + 1) & 1], tid, wave);

    if (jt <= lasttile) {                    // wave-uniform; B-waves always active
      const unsigned short* kb = k_lds[jt & 1];
      const unsigned short* vb = v_lds[jt & 1];
      const int j0 = jt * 64;

      bf16x8 kf[8];
#pragma unroll
      for (int i = 0; i < 4; ++i) {
        kf[2 * i]     = *(const bf16x8*)(kb + (16 * i + l16) * 64 + kcol0);
        kf[2 * i + 1] = *(const bf16x8*)(kb + (16 * i + l16) * 64 + (kcol0 ^ 32));
      }

      f32x4 s0[4], s1[4];
      qk_score(kf, qf0, s0);
      qk_score(kf, qf1, s1);

      bf16x8 pf0[2], pf1[2];
      if (jt == lasttile) {
        exp_pack<true>(s0, j0, q0 + l16,      l16, quad, ls0, pf0);
        exp_pack<true>(s1, j0, q0 + 16 + l16, l16, quad, ls1, pf1);
      } else {
        exp_pack<false>(s0, j0, q0 + l16,      l16, quad, ls0, pf0);
        exp_pack<false>(s1, j0, q0 + 16 + l16, l16, quad, ls1, pf1);
      }

      pv_dual(vb, l16, quad, x7, pf0, pf1, o0, o1);
    }
  }

  // full row-sums: reduce partial sums across the 4 quads
  ls0 += __shfl_xor(ls0, 16); ls0 += __shfl_xor(ls0, 32);
  ls1 += __shfl_xor(ls1, 16); ls1 += __shfl_xor(ls1, 32);
  const float inv0 = 1.0f / ls0, inv1 = 1.0f / ls1;

  // O: col=l16=q, row = dt*16 + quad*4 + r = d
  const int b = bh / NHEAD, hd = bh - b * NHEAD;
  unsigned short* yr0 = y + (size_t)(b * TSEQ + q0 + l16) * CDIM + hd * 64 + quad * 4;
  unsigned short* yr1 = yr0 + (size_t)16 * CDIM;
#pragma unroll
  for (int dt = 0; dt < 4; ++dt) {
    uint2 w0, w1;
    w0.x = pack2bf(o0[dt][0] * inv0, o0[dt][1] * inv0);
    w0.y = pack2bf(o0[dt][2] * inv0, o0[dt][3] * inv0);
    w1.x = pack2bf(o1[dt][0] * inv1, o1[dt][1] * inv1);
    w1.y = pack2bf(o1[dt][2] * inv1, o1[dt][3] * inv1);
    *(uint2*)(yr0 + dt * 16) = w0;
    *(uint2*)(yr1 + dt * 16) = w1;
  }
}

// ---------------- launch ----------------

extern "C" void kernel_launch(void* const* d_in, const int* in_sizes, int n_in,
                              void* d_out, int out_size, void* d_ws, size_t ws_size,
                              hipStream_t stream) {
  const float* x      = (const float*)d_in[0];
  const float* W_attn = (const float*)d_in[1];
  const float* b_attn = (const float*)d_in[2];
  const float* W_proj = (const float*)d_in[3];
  const float* b_proj = (const float*)d_in[4];
  float* out = (float*)d_out;

  unsigned short* xb    = (unsigned short*)d_ws;                  // [8192,768] bf16 (later reused as y)
  unsigned short* WaT   = xb + (size_t)BT_TOT * CDIM;             // [2304,768]
  unsigned short* WpT   = WaT + (size_t)C3 * CDIM;                // [768,768]
  unsigned short* qbuf  = WpT + (size_t)CDIM * CDIM;              // [24,4096,64]
  unsigned short* kbuf  = qbuf + (size_t)2 * NHEAD * TSEQ * 64;   // [24,4096,64]
  unsigned short* vtbuf = kbuf + (size_t)2 * NHEAD * TSEQ * 64;   // [24,64,4096] (key-permuted)
  unsigned short* ybuf  = xb;  // x dead after GEMM1

  cast_f32_bf16<<<(BT_TOT * CDIM) / 1024, 256, 0, stream>>>(x, xb, BT_TOT * CDIM);
  transpose_cast<<<dim3(C3 / 32, CDIM / 32), dim3(32, 8), 0, stream>>>(W_attn, WaT, CDIM, C3);
  transpose_cast<<<dim3(CDIM / 32, CDIM / 32), dim3(32, 8), 0, stream>>>(W_proj, WpT, CDIM, CDIM);

  gemm_qkv_kernel<<<dim3(C3 / 128, BT_TOT / 128), 256, 0, stream>>>(xb, WaT, b_attn,
                                                                    qbuf, kbuf, vtbuf);
  attn_kernel<<<dim3(24 * 32), 256, 0, stream>>>(qbuf, kbuf, vtbuf, ybuf);
  gemm_out_kernel<<<dim3(CDIM / 128, BT_TOT / 128), 256, 0, stream>>>(ybuf, WpT, b_proj, out);
}

// Round 11
// 227.268 us; speedup vs baseline: 1.8149x; 1.0038x over previous
//
#include <hip/hip_runtime.h>

// Causal self-attention, B=2 T=4096 C=768 H=12 D=64, bf16 MFMA pipeline:
//   cast x -> bf16; transpose W_attn/W_proj -> [N,K] bf16
//   GEMM1 (x @ W_attn + b) -> Q[b,h,t,d], K[b,h,t,d] (pre-scaled by log2e/8),
//     V^T[b,h,d,t'] where t' is PER-64-TILE KEY-PERMUTED: key i*16+q4*4+r stored at
//     (i>>1)*32 + q4*8 + (i&1)*4 + r (feeds attention's in-register PV path).
//   GEMM mainloops: 3-BUFFER COUNTED-VMCNT pipeline (R8's 1-deep dbuf left GEMM1 at
//     ~65us: per-iter compute ~200cy < stage latency 300-900cy, and __syncthreads'
//     vmcnt(0) drain stalled every iter). Now: stage 3 tiles ahead; per iter
//     wait vmcnt(8) (stage(t) landed, t+1/t+2 in flight) -> s_barrier -> compute ->
//     s_barrier -> restage buf[t%3]. Latency covered 3 iters deep; never drain to 0
//     in the loop (catalog T4).
//   attention: R8 version verbatim (70.5us, SQ_LDS_BANK_CONFLICT=0, ~87% of the
//     85B/cy LDS ceiling at its geometry). R9 (direct-K: L1 thrash, 270us) and
//     R10 (dual-chunk: occupancy loss, 82us) both refuted; R8 needs >=24 waves/CU.
//   GEMM2 (y @ W_proj + b) -> out fp32

#define TSEQ   4096
#define NHEAD  12
#define CDIM   768
#define C3     2304
#define BT_TOT 8192   // B*T

typedef __bf16 bf16x8 __attribute__((ext_vector_type(8)));
typedef __bf16 bf16x2 __attribute__((ext_vector_type(2)));
typedef float  f32x4  __attribute__((ext_vector_type(4)));
typedef unsigned int u32x4 __attribute__((ext_vector_type(4)));

__device__ __forceinline__ unsigned short f2bf(float f) {
  unsigned int u = __builtin_bit_cast(unsigned int, f);
  u += 0x7FFFu + ((u >> 16) & 1u);            // round-to-nearest-even
  return (unsigned short)(u >> 16);
}

// native gfx950 f32->bf16 (v_cvt_pk_bf16_f32) — 1 instr per pair
__device__ __forceinline__ unsigned int pack2bf(float a, float b) {
  bf16x2 v = {(__bf16)a, (__bf16)b};
  return __builtin_bit_cast(unsigned int, v);
}

__device__ __forceinline__ f32x4 mfma16(bf16x8 a, bf16x8 b, f32x4 c) {
  return __builtin_amdgcn_mfma_f32_16x16x32_bf16(a, b, c, 0, 0, 0);
}

typedef const __attribute__((address_space(1))) void* gas_ptr;
typedef __attribute__((address_space(3))) void* las_ptr;

// s_waitcnt masks: bits[3:0]=vmcnt[3:0], [6:4]=expcnt, [13:8]=lgkmcnt, [15:14]=vmcnt[5:4]
#define WAIT_VM8() __builtin_amdgcn_s_waitcnt(0x3F78)   // vmcnt<=8, lgkm/exp free
#define WAIT_VM4() __builtin_amdgcn_s_waitcnt(0x3F74)   // vmcnt<=4
#define WAIT_VM0() __builtin_amdgcn_s_waitcnt(0x3F70)   // vmcnt<=0

// ---------------- prologue casts ----------------

__global__ __launch_bounds__(256) void cast_f32_bf16(const float* __restrict__ x,
                                                     unsigned short* __restrict__ o, int n) {
  int i = (blockIdx.x * 256 + threadIdx.x) * 4;
  if (i < n) {
    float4 v = *(const float4*)(x + i);
    ushort4 u;
    u.x = f2bf(v.x); u.y = f2bf(v.y); u.z = f2bf(v.z); u.w = f2bf(v.w);
    *(ushort4*)(o + i) = u;
  }
}

// dst[n][k] = bf16(src[k][n]);  K,N multiples of 32
__global__ __launch_bounds__(256) void transpose_cast(const float* __restrict__ src,
                                                      unsigned short* __restrict__ dst,
                                                      int K, int N) {
  __shared__ float tile[32][33];
  int n0 = blockIdx.x * 32, k0 = blockIdx.y * 32;
  int tx = threadIdx.x, ty = threadIdx.y;  // 32 x 8
#pragma unroll
  for (int i = 0; i < 4; ++i)
    tile[ty + i * 8][tx] = src[(size_t)(k0 + ty + i * 8) * N + n0 + tx];
  __syncthreads();
#pragma unroll
  for (int i = 0; i < 4; ++i)
    dst[(size_t)(n0 + ty + i * 8) * K + k0 + tx] = f2bf(tile[tx][ty + i * 8]);
}

// ---------------- GEMM core (C = A[M,K] * BT[N,K]^T), 128x128 tile, BK=32 ----------------
// 3-buffer counted-vmcnt pipeline: buf b (shorts) at b*8192 + {A: 0..4095, B: 4096..8191}.

__device__ __forceinline__ void stage_gemm(const unsigned short* __restrict__ A,
                                           const unsigned short* __restrict__ BTm,
                                           int K, int m0, int n0, int k0,
                                           unsigned short* buf, int wave,
                                           int srow, int scol) {
#pragma unroll
  for (int r = 0; r < 2; ++r) {
    const unsigned short* ga = A + (size_t)(m0 + r * 64 + srow) * K + k0 + scol;
    __builtin_amdgcn_global_load_lds((gas_ptr)ga,
        (las_ptr)(buf + r * 2048 + wave * 512), 16, 0, 0);
    const unsigned short* gb = BTm + (size_t)(n0 + r * 64 + srow) * K + k0 + scol;
    __builtin_amdgcn_global_load_lds((gas_ptr)gb,
        (las_ptr)(buf + 4096 + r * 2048 + wave * 512), 16, 0, 0);
  }
}

__device__ __forceinline__ void gemm_bt_mainloop(const unsigned short* __restrict__ A,
                                                 const unsigned short* __restrict__ BTm,
                                                 int K, int m0, int n0,
                                                 unsigned short* lds, f32x4 acc[4][4]) {
  const int tid = threadIdx.x;
  const int wave = tid >> 6, lane = tid & 63;
  const int quad = lane >> 4, l16 = lane & 15;
  const int wm = (wave >> 1) * 64, wn = (wave & 1) * 64;
  const int srow = tid >> 2;          // 0..63
  const int scol = (tid & 3) * 8;     // shorts

  const int nt = K / 32;              // 24 for K=768
  stage_gemm(A, BTm, K, m0, n0, 0,  lds,         wave, srow, scol);
  stage_gemm(A, BTm, K, m0, n0, 32, lds + 8192,  wave, srow, scol);
  stage_gemm(A, BTm, K, m0, n0, 64, lds + 16384, wave, srow, scol);

  for (int t = 0; t < nt; ++t) {
    // my stage(t) landed; up to 2 later stages (8 loads) stay in flight (T4: never 0)
    const int rem = nt - 1 - t;
    if (rem >= 2)      WAIT_VM8();
    else if (rem == 1) WAIT_VM4();
    else               WAIT_VM0();
    __builtin_amdgcn_sched_barrier(0);
    __builtin_amdgcn_s_barrier();     // all waves' stage(t) slices landed

    const unsigned short* buf = lds + (t % 3) * 8192;
    bf16x8 af[4], bfr[4];
#pragma unroll
    for (int i = 0; i < 4; ++i) {
      af[i]  = *(const bf16x8*)(buf + (wm + i * 16 + l16) * 32 + quad * 8);
      bfr[i] = *(const bf16x8*)(buf + 4096 + (wn + i * 16 + l16) * 32 + quad * 8);
    }
#pragma unroll
    for (int i = 0; i < 4; ++i)
#pragma unroll
      for (int j = 0; j < 4; ++j)
        acc[i][j] = mfma16(af[i], bfr[j], acc[i][j]);

    __builtin_amdgcn_s_barrier();     // all waves done reading buf[t%3]
    __builtin_amdgcn_sched_barrier(0);
    if (t + 3 < nt)                   // safe: issued only after the read-done barrier
      stage_gemm(A, BTm, K, m0, n0, (t + 3) * 32, lds + (t % 3) * 8192, wave, srow, scol);
  }
  __syncthreads();                    // full drain before epilogue LDS reuse
}

// GEMM1: qkv = x@W_attn + b_attn -> Q/K (b,h,t,d) and key-permuted V^T (b,h,d,t'), bf16.
// K pre-scaled by log2e/8. Epilogue: tile -> LDS (transposed for V), then coalesced
// 16B stores; the V path gathers 2x8B per 16B chunk to apply the per-64 key permutation
// col'(key) = (key>>5)*32 + ((key>>2)&3)*8 + ((key>>4)&1)*4 + (key&3).
__global__ __launch_bounds__(256, 3) void gemm_qkv_kernel(
    const unsigned short* __restrict__ A, const unsigned short* __restrict__ BTm,
    const float* __restrict__ bias,
    unsigned short* __restrict__ qbuf, unsigned short* __restrict__ kbuf,
    unsigned short* __restrict__ vtbuf) {
  __shared__ __align__(16) unsigned short lds[3 * 8192];  // 48KB pipeline; epilogue reuses 34KB
  f32x4 zero = {0.f, 0.f, 0.f, 0.f};
  f32x4 acc[4][4];
#pragma unroll
  for (int i = 0; i < 4; ++i)
#pragma unroll
    for (int j = 0; j < 4; ++j) acc[i][j] = zero;

  const int m0 = blockIdx.y * 128, n0 = blockIdx.x * 128;
  gemm_bt_mainloop(A, BTm, CDIM, m0, n0, lds, acc);
  // mainloop's final __syncthreads: all waves synced, LDS reusable

  const int tid = threadIdx.x;
  const int wave = tid >> 6, lane = tid & 63;
  const int quad = lane >> 4, l16 = lane & 15;
  const int wm = (wave >> 1) * 64, wn = (wave & 1) * 64;
  const float KSCALE = 0.125f * 1.44269504088896340736f;  // 1/sqrt(64) * log2(e)

  const int seg = n0 / CDIM;   // 0=Q 1=K 2=V — uniform per block (128 | 768)
  const float mult = (seg == 1) ? KSCALE : 1.0f;

#pragma unroll
  for (int j = 0; j < 4; ++j) {
    const int nl = wn + j * 16 + l16;
    const float bv = bias[n0 + nl];
#pragma unroll
    for (int i = 0; i < 4; ++i) {
#pragma unroll
      for (int r = 0; r < 4; ++r) {
        const int ml = wm + i * 16 + quad * 4 + r;
        unsigned short val = f2bf((acc[i][j][r] + bv) * mult);
        if (seg < 2) lds[ml * 136 + nl] = val;   // [t][n] for Q/K
        else         lds[nl * 136 + ml] = val;   // [n][t] for V^T
      }
    }
  }
  __syncthreads();

  const int row = tid >> 1, half = tid & 1;
  const unsigned short* src = lds + row * 136 + half * 64;
  if (seg < 2) {
    const int m = m0 + row, b = m >> 12, t = m & (TSEQ - 1);
    const int nn = (n0 - seg * CDIM) + half * 64;   // multiple of 64
    const int h = nn >> 6;
    unsigned short* base = (seg == 0) ? qbuf : kbuf;
    unsigned short* dst = base + ((size_t)(b * NHEAD + h) * TSEQ + t) * 64;
#pragma unroll
    for (int k = 0; k < 8; ++k)
      *(uint4*)(dst + k * 8) = *(const uint4*)(src + k * 8);
  } else {
    const int nn = (n0 - 2 * CDIM) + row;
    const int h = nn >> 6, d = nn & 63;
    const int b = m0 >> 12, t0 = (m0 & (TSEQ - 1)) + half * 64;
    unsigned short* dst = vtbuf + ((size_t)(b * NHEAD + h) * 64 + d) * TSEQ + t0;
    // permuted store: dst chunk k holds keys {2(k>>2)}*16+(k&3)*4+0..3 then +16
#pragma unroll
    for (int k = 0; k < 8; ++k) {
      const int s0 = 32 * (k >> 2) + 4 * (k & 3);
      uint2 a = *(const uint2*)(src + s0);
      uint2 c = *(const uint2*)(src + s0 + 16);
      uint4 w = {a.x, a.y, c.x, c.y};
      *(uint4*)(dst + k * 8) = w;
    }
  }
}

// GEMM2: out = y@W_proj + b_proj (fp32 out)
__global__ __launch_bounds__(256, 3) void gemm_out_kernel(
    const unsigned short* __restrict__ A, const unsigned short* __restrict__ BTm,
    const float* __restrict__ bias, float* __restrict__ out) {
  __shared__ __align__(16) unsigned short lds[3 * 8192];   // 48KB pipeline
  f32x4 zero = {0.f, 0.f, 0.f, 0.f};
  f32x4 acc[4][4];
#pragma unroll
  for (int i = 0; i < 4; ++i)
#pragma unroll
    for (int j = 0; j < 4; ++j) acc[i][j] = zero;

  const int m0 = blockIdx.y * 128, n0 = blockIdx.x * 128;
  gemm_bt_mainloop(A, BTm, CDIM, m0, n0, lds, acc);

  const int tid = threadIdx.x;
  const int wave = tid >> 6, lane = tid & 63;
  const int quad = lane >> 4, l16 = lane & 15;
  const int wm = (wave >> 1) * 64, wn = (wave & 1) * 64;

#pragma unroll
  for (int j = 0; j < 4; ++j) {
    int n = n0 + wn + j * 16 + l16;
    float bv = bias[n];
#pragma unroll
    for (int i = 0; i < 4; ++i) {
#pragma unroll
      for (int r = 0; r < 4; ++r) {
        int m = m0 + wm + i * 16 + quad * 4 + r;
        out[(size_t)m * CDIM + n] = acc[i][j][r] + bv;
      }
    }
  }
}

// ---------------- attention (R8 version verbatim) ----------------
// S^T: A=K (m=key=l16 within 16-group, k=d=quad*8+j), B=Q (n=q=l16).
// C: col=l16=q, row=quad*4+r=key -> P lane-local (16 values: keys 16i+quad*4+r).
// PV (16x16x32): A = permuted V^T from LDS — ONE 16B read per frag (k-slot quad*8+i*4+r
// carries key 16(2f+i)+quad*4+r, f=frag); B = pack2bf(s-regs) in matching order.
// O C: col=l16=q, row=quad*4+r=d (+16dt) -> per-row norm via quad shfl-reduce.

// 512 threads stage one 64x64 K tile + one 64x64 (permuted) V^T tile (16B/lane each).
__device__ __forceinline__ void stage_kv(const unsigned short* __restrict__ Kp,
                                         const unsigned short* __restrict__ Vp,
                                         int j0, unsigned short* kb, unsigned short* vb,
                                         int tid, int wave) {
  const int row = tid >> 3;                              // 0..63
  const int col = ((tid & 7) ^ (row & 7)) * 8;           // XOR swizzle (self-inverse)
  __builtin_amdgcn_global_load_lds((gas_ptr)(Kp + (size_t)(j0 + row) * 64 + col),
                                   (las_ptr)(kb + wave * 512), 16, 0, 0);
  __builtin_amdgcn_global_load_lds((gas_ptr)(Vp + (size_t)row * TSEQ + j0 + col),
                                   (las_ptr)(vb + wave * 512), 16, 0, 0);
}

__device__ __forceinline__ void qk_score(const bf16x8 kf[8], const bf16x8 qf[2], f32x4 s[4]) {
  f32x4 zero = {0.f, 0.f, 0.f, 0.f};
#pragma unroll
  for (int i = 0; i < 4; ++i)
    s[i] = mfma16(kf[2 * i + 1], qf[1], mfma16(kf[2 * i], qf[0], zero));
}

// exp2 + (diagonal) causal mask + lane-local partial row-sum; packs P into the two
// PV B-frags (k-slot order quad*8 + i*4 + r == permuted V^T storage order).
template <bool MASKED>
__device__ __forceinline__ void exp_pack(const f32x4 s[4], int j0, int qabs,
                                         int l16, int quad, float& lsum, bf16x8 pf[2]) {
  unsigned int w[8];
#pragma unroll
  for (int i = 0; i < 4; ++i) {
    float p[4];
#pragma unroll
    for (int r = 0; r < 4; ++r) {
      p[r] = __builtin_amdgcn_exp2f(s[i][r]);
      if (MASKED) {
        if (j0 + i * 16 + quad * 4 + r > qabs) p[r] = 0.f;
      }
      lsum += p[r];
    }
    w[2 * i]     = pack2bf(p[0], p[1]);
    w[2 * i + 1] = pack2bf(p[2], p[3]);
  }
  u32x4 lo = {w[0], w[1], w[2], w[3]};   // keys i=0,1 at k-slots quad*8 + 0..7
  u32x4 hi = {w[4], w[5], w[6], w[7]};   // keys i=2,3
  pf[0] = __builtin_bit_cast(bf16x8, lo);
  pf[1] = __builtin_bit_cast(bf16x8, hi);
}

// PV: 8 mfma16 off 8 conflict-free 16B v reads (frag0 block=quad, frag1 block=4+quad,
// de-swizzled by x7 = l16&7; rows d = dt*16+l16).
__device__ __forceinline__ void pv(const unsigned short* __restrict__ vb,
                                   int l16, int quad, int x7,
                                   const bf16x8 pf[2], f32x4 o[4]) {
#pragma unroll
  for (int dt = 0; dt < 4; ++dt) {
    const unsigned short* vr = vb + (dt * 16 + l16) * 64;
    bf16x8 v0 = *(const bf16x8*)(vr + ((quad ^ x7) * 8));
    bf16x8 v1 = *(const bf16x8*)(vr + (((4 + quad) ^ x7) * 8));
    o[dt] = mfma16(v1, pf[1], mfma16(v0, pf[0], o[dt]));
  }
}

__global__ __launch_bounds__(512, 6) void attn_kernel(const unsigned short* __restrict__ qbuf,
                                                      const unsigned short* __restrict__ kbuf,
                                                      const unsigned short* __restrict__ vtbuf,
                                                      unsigned short* __restrict__ y) {
  __shared__ __align__(16) unsigned short k_lds[2][64 * 64];      // 2 x 8KB
  __shared__ __align__(16) unsigned short v_lds[2][64 * 64];      // 2 x 8KB

  const int tid = threadIdx.x;
  const int wave = tid >> 6, lane = tid & 63;
  const int quad = lane >> 4, l16 = lane & 15;
  const int x7 = l16 & 7;

  const int bh = blockIdx.x % 24;
  const int p = blockIdx.x / 24;            // 0..31; p=0 (longest stream) dispatches first
  const bool isA = wave < 4;                // waves 0-3: q-tile p; waves 4-7: q-tile 63-p
  const int qtile = isA ? p : (63 - p);
  const int q0 = qtile * 64 + (wave & 3) * 16;

  const unsigned short* Qp = qbuf + (size_t)bh * TSEQ * 64;
  const unsigned short* Kp = kbuf + (size_t)bh * TSEQ * 64;
  const unsigned short* Vp = vtbuf + (size_t)bh * 64 * TSEQ;

  bf16x8 qf[2];
  qf[0] = *(const bf16x8*)(Qp + (size_t)(q0 + l16) * 64 + quad * 8);
  qf[1] = *(const bf16x8*)(Qp + (size_t)(q0 + l16) * 64 + 32 + quad * 8);

  f32x4 zero = {0.f, 0.f, 0.f, 0.f};
  f32x4 o[4];
#pragma unroll
  for (int dt = 0; dt < 4; ++dt) o[dt] = zero;
  float ls = 0.f;

  const int kcol0 = (quad ^ x7) * 8;          // swizzled K frag column (shorts)
  const int ntiles = 64 - p;                  // key tiles 0..63-p
  const int lasttile = isA ? p : (ntiles - 1);// this wave's diagonal tile (== qtile)

  stage_kv(Kp, Vp, 0, k_lds[0], v_lds[0], tid, wave);

  for (int jt = 0; jt < ntiles; ++jt) {
    __syncthreads();   // stage(jt) visible; other buffer free for restage
    if (jt + 1 < ntiles)
      stage_kv(Kp, Vp, (jt + 1) * 64, k_lds[(jt + 1) & 1], v_lds[(jt + 1) & 1], tid, wave);

    if (jt <= lasttile) {                    // wave-uniform; B-waves always active
      const unsigned short* kb = k_lds[jt & 1];
      const unsigned short* vb = v_lds[jt & 1];
      const int j0 = jt * 64;

      bf16x8 kf[8];
#pragma unroll
      for (int i = 0; i < 4; ++i) {
        kf[2 * i]     = *(const bf16x8*)(kb + (16 * i + l16) * 64 + kcol0);
        kf[2 * i + 1] = *(const bf16x8*)(kb + (16 * i + l16) * 64 + (kcol0 ^ 32));
      }

      f32x4 s[4];
      qk_score(kf, qf, s);

      bf16x8 pf[2];
      if (jt == lasttile) exp_pack<true>(s, j0, q0 + l16, l16, quad, ls, pf);
      else                exp_pack<false>(s, j0, q0 + l16, l16, quad, ls, pf);

      pv(vb, l16, quad, x7, pf, o);
    }
  }

  // full row-sum for q=l16: reduce partial sums across the 4 quads
  ls += __shfl_xor(ls, 16); ls += __shfl_xor(ls, 32);
  const float inv = 1.0f / ls;

  // O: col=l16=q (t = q0+l16), row = dt*16 + quad*4 + r = d
  const int b = bh / NHEAD, hd = bh - b * NHEAD;
  unsigned short* yr = y + (size_t)(b * TSEQ + q0 + l16) * CDIM + hd * 64 + quad * 4;
#pragma unroll
  for (int dt = 0; dt < 4; ++dt) {
    uint2 w;
    w.x = pack2bf(o[dt][0] * inv, o[dt][1] * inv);
    w.y = pack2bf(o[dt][2] * inv, o[dt][3] * inv);
    *(uint2*)(yr + dt * 16) = w;
  }
}

// ---------------- launch ----------------

extern "C" void kernel_launch(void* const* d_in, const int* in_sizes, int n_in,
                              void* d_out, int out_size, void* d_ws, size_t ws_size,
                              hipStream_t stream) {
  const float* x      = (const float*)d_in[0];
  const float* W_attn = (const float*)d_in[1];
  const float* b_attn = (const float*)d_in[2];
  const float* W_proj = (const float*)d_in[3];
  const float* b_proj = (const float*)d_in[4];
  float* out = (float*)d_out;

  unsigned short* xb    = (unsigned short*)d_ws;                  // [8192,768] bf16 (later reused as y)
  unsigned short* WaT   = xb + (size_t)BT_TOT * CDIM;             // [2304,768]
  unsigned short* WpT   = WaT + (size_t)C3 * CDIM;                // [768,768]
  unsigned short* qbuf  = WpT + (size_t)CDIM * CDIM;              // [24,4096,64]
  unsigned short* kbuf  = qbuf + (size_t)2 * NHEAD * TSEQ * 64;   // [24,4096,64]
  unsigned short* vtbuf = kbuf + (size_t)2 * NHEAD * TSEQ * 64;   // [24,64,4096] (key-permuted)
  unsigned short* ybuf  = xb;  // x dead after GEMM1

  cast_f32_bf16<<<(BT_TOT * CDIM) / 1024, 256, 0, stream>>>(x, xb, BT_TOT * CDIM);
  transpose_cast<<<dim3(C3 / 32, CDIM / 32), dim3(32, 8), 0, stream>>>(W_attn, WaT, CDIM, C3);
  transpose_cast<<<dim3(CDIM / 32, CDIM / 32), dim3(32, 8), 0, stream>>>(W_proj, WpT, CDIM, CDIM);

  gemm_qkv_kernel<<<dim3(C3 / 128, BT_TOT / 128), 256, 0, stream>>>(xb, WaT, b_attn,
                                                                    qbuf, kbuf, vtbuf);
  attn_kernel<<<dim3(24 * 32), 512, 0, stream>>>(qbuf, kbuf, vtbuf, ybuf);
  gemm_out_kernel<<<dim3(CDIM / 128, BT_TOT / 128), 256, 0, stream>>>(ybuf, WpT, b_proj, out);
}

// Round 13
// 222.775 us; speedup vs baseline: 1.8515x; 1.0202x over previous
//
#include <hip/hip_runtime.h>

// Causal self-attention, B=2 T=4096 C=768 H=12 D=64, bf16 MFMA pipeline:
//   prep (ONE fused kernel: R11 accounting showed kernel sum ~163us vs 226 total ->
//     ~60us of launch/dispatch overhead across 6 serial kernels; fusing the 3
//     independent prologue jobs deletes 2 boundaries and runs them concurrently):
//     cast x -> bf16; transpose W_attn/W_proj -> [N,K] bf16.
//   GEMM1 (x @ W_attn + b) -> Q[b,h,t,d], K[b,h,t,d] (pre-scaled by log2e/8),
//     V^T[b,h,d,t'] where t' is PER-64-TILE KEY-PERMUTED: key i*16+q4*4+r stored at
//     (i>>1)*32 + q4*8 + (i&1)*4 + r (feeds attention's in-register PV path).
//   GEMM mainloops: R8's 2-phase double-buffer (R11's 3-deep counted-vmcnt was
//     neutral -> structure, not prefetch depth, limits; keep the simpler loop).
//   attention: R8 version verbatim (70.5us, conflicts=0, ~87% of the 85B/cy LDS
//     ceiling at its geometry; R9 direct-K and R10 dual-chunk both refuted).
//   GEMM2 (y @ W_proj + b) -> out fp32
//   (round-12 bench was an infra failure "container failed twice"; prep_kernel
//    re-audited — indexing in-bounds, barriers block-uniform — resubmitted unchanged.)

#define TSEQ   4096
#define NHEAD  12
#define CDIM   768
#define C3     2304
#define BT_TOT 8192   // B*T

typedef __bf16 bf16x8 __attribute__((ext_vector_type(8)));
typedef __bf16 bf16x2 __attribute__((ext_vector_type(2)));
typedef float  f32x4  __attribute__((ext_vector_type(4)));
typedef unsigned int u32x4 __attribute__((ext_vector_type(4)));

__device__ __forceinline__ unsigned short f2bf(float f) {
  unsigned int u = __builtin_bit_cast(unsigned int, f);
  u += 0x7FFFu + ((u >> 16) & 1u);            // round-to-nearest-even
  return (unsigned short)(u >> 16);
}

// native gfx950 f32->bf16 (v_cvt_pk_bf16_f32) — 1 instr per pair
__device__ __forceinline__ unsigned int pack2bf(float a, float b) {
  bf16x2 v = {(__bf16)a, (__bf16)b};
  return __builtin_bit_cast(unsigned int, v);
}

__device__ __forceinline__ f32x4 mfma16(bf16x8 a, bf16x8 b, f32x4 c) {
  return __builtin_amdgcn_mfma_f32_16x16x32_bf16(a, b, c, 0, 0, 0);
}

typedef const __attribute__((address_space(1))) void* gas_ptr;
typedef __attribute__((address_space(3))) void* las_ptr;

// ---------------- fused prologue ----------------
// blocks [0,6144): cast x (4 f32/thread); [6144,7872): W_attn^T; [7872,8448): W_proj^T.
// Branch is block-uniform; __syncthreads only on the transpose path (all its threads reach it).

#define PREP_CAST_BLOCKS  6144   // 8192*768 / (256*4)
#define PREP_WA_BLOCKS    1728   // (2304/32)*(768/32)
#define PREP_WP_BLOCKS     576   // (768/32)*(768/32)

__global__ __launch_bounds__(256) void prep_kernel(
    const float* __restrict__ x, unsigned short* __restrict__ xb,
    const float* __restrict__ W_attn, unsigned short* __restrict__ WaT,
    const float* __restrict__ W_proj, unsigned short* __restrict__ WpT) {
  const int bk = blockIdx.x;
  if (bk < PREP_CAST_BLOCKS) {
    int i = (bk * 256 + threadIdx.x) * 4;
    float4 v = *(const float4*)(x + i);
    ushort4 u;
    u.x = f2bf(v.x); u.y = f2bf(v.y); u.z = f2bf(v.z); u.w = f2bf(v.w);
    *(ushort4*)(xb + i) = u;
    return;
  }
  __shared__ float tile[32][33];
  const float* src;
  unsigned short* dst;
  int K, N, n0, k0;
  if (bk < PREP_CAST_BLOCKS + PREP_WA_BLOCKS) {
    const int j = bk - PREP_CAST_BLOCKS;
    src = W_attn; dst = WaT; K = CDIM; N = C3;
    n0 = (j % 72) * 32; k0 = (j / 72) * 32;
  } else {
    const int j = bk - (PREP_CAST_BLOCKS + PREP_WA_BLOCKS);
    src = W_proj; dst = WpT; K = CDIM; N = CDIM;
    n0 = (j % 24) * 32; k0 = (j / 24) * 32;
  }
  const int tx = threadIdx.x & 31, ty = threadIdx.x >> 5;  // 32 x 8
#pragma unroll
  for (int i = 0; i < 4; ++i)
    tile[ty + i * 8][tx] = src[(size_t)(k0 + ty + i * 8) * N + n0 + tx];
  __syncthreads();
#pragma unroll
  for (int i = 0; i < 4; ++i)
    dst[(size_t)(n0 + ty + i * 8) * K + k0 + tx] = f2bf(tile[tx][ty + i * 8]);
}

// ---------------- GEMM core (C = A[M,K] * BT[N,K]^T), 128x128 tile, BK=32 ----------------
// 2-phase double-buffered: buf layout (shorts) cur*8192 + {A: 0..4095, B: 4096..8191}.

__device__ __forceinline__ void stage_gemm(const unsigned short* __restrict__ A,
                                           const unsigned short* __restrict__ BTm,
                                           int K, int m0, int n0, int k0,
                                           unsigned short* buf, int wave,
                                           int srow, int scol) {
#pragma unroll
  for (int r = 0; r < 2; ++r) {
    const unsigned short* ga = A + (size_t)(m0 + r * 64 + srow) * K + k0 + scol;
    __builtin_amdgcn_global_load_lds((gas_ptr)ga,
        (las_ptr)(buf + r * 2048 + wave * 512), 16, 0, 0);
    const unsigned short* gb = BTm + (size_t)(n0 + r * 64 + srow) * K + k0 + scol;
    __builtin_amdgcn_global_load_lds((gas_ptr)gb,
        (las_ptr)(buf + 4096 + r * 2048 + wave * 512), 16, 0, 0);
  }
}

__device__ __forceinline__ void gemm_bt_mainloop(const unsigned short* __restrict__ A,
                                                 const unsigned short* __restrict__ BTm,
                                                 int K, int m0, int n0,
                                                 unsigned short* lds, f32x4 acc[4][4]) {
  const int tid = threadIdx.x;
  const int wave = tid >> 6, lane = tid & 63;
  const int quad = lane >> 4, l16 = lane & 15;
  const int wm = (wave >> 1) * 64, wn = (wave & 1) * 64;
  const int srow = tid >> 2;          // 0..63
  const int scol = (tid & 3) * 8;     // shorts

  stage_gemm(A, BTm, K, m0, n0, 0, lds, wave, srow, scol);
  __syncthreads();                    // prologue stage visible

  int cur = 0;
  for (int k0 = 0; k0 < K; k0 += 32) {
    if (k0 + 32 < K)                  // issue next-tile loads FIRST (overlap with MFMA)
      stage_gemm(A, BTm, K, m0, n0, k0 + 32, lds + (cur ^ 1) * 8192, wave, srow, scol);

    const unsigned short* buf = lds + cur * 8192;
    bf16x8 af[4], bfr[4];
#pragma unroll
    for (int i = 0; i < 4; ++i) {
      af[i]  = *(const bf16x8*)(buf + (wm + i * 16 + l16) * 32 + quad * 8);
      bfr[i] = *(const bf16x8*)(buf + 4096 + (wn + i * 16 + l16) * 32 + quad * 8);
    }
#pragma unroll
    for (int i = 0; i < 4; ++i)
#pragma unroll
      for (int j = 0; j < 4; ++j)
        acc[i][j] = mfma16(af[i], bfr[j], acc[i][j]);

    __syncthreads();   // single barrier: drains stage(t+1) (vmcnt) + my ds_reads (lgkm)
    cur ^= 1;
  }
}

// GEMM1: qkv = x@W_attn + b_attn -> Q/K (b,h,t,d) and key-permuted V^T (b,h,d,t'), bf16.
// K pre-scaled by log2e/8. Epilogue: tile -> LDS (transposed for V), then coalesced
// 16B stores; the V path gathers 2x8B per 16B chunk to apply the per-64 key permutation
// col'(key) = (key>>5)*32 + ((key>>2)&3)*8 + ((key>>4)&1)*4 + (key&3).
__global__ __launch_bounds__(256, 4) void gemm_qkv_kernel(
    const unsigned short* __restrict__ A, const unsigned short* __restrict__ BTm,
    const float* __restrict__ bias,
    unsigned short* __restrict__ qbuf, unsigned short* __restrict__ kbuf,
    unsigned short* __restrict__ vtbuf) {
  __shared__ __align__(16) unsigned short lds[128 * 136];  // mainloop dbuf uses first 16384
  f32x4 zero = {0.f, 0.f, 0.f, 0.f};
  f32x4 acc[4][4];
#pragma unroll
  for (int i = 0; i < 4; ++i)
#pragma unroll
    for (int j = 0; j < 4; ++j) acc[i][j] = zero;

  const int m0 = blockIdx.y * 128, n0 = blockIdx.x * 128;
  gemm_bt_mainloop(A, BTm, CDIM, m0, n0, lds, acc);
  // mainloop's final barrier: all waves synced, all LDS reads drained -> safe to reuse

  const int tid = threadIdx.x;
  const int wave = tid >> 6, lane = tid & 63;
  const int quad = lane >> 4, l16 = lane & 15;
  const int wm = (wave >> 1) * 64, wn = (wave & 1) * 64;
  const float KSCALE = 0.125f * 1.44269504088896340736f;  // 1/sqrt(64) * log2(e)

  const int seg = n0 / CDIM;   // 0=Q 1=K 2=V — uniform per block (128 | 768)
  const float mult = (seg == 1) ? KSCALE : 1.0f;

#pragma unroll
  for (int j = 0; j < 4; ++j) {
    const int nl = wn + j * 16 + l16;
    const float bv = bias[n0 + nl];
#pragma unroll
    for (int i = 0; i < 4; ++i) {
#pragma unroll
      for (int r = 0; r < 4; ++r) {
        const int ml = wm + i * 16 + quad * 4 + r;
        unsigned short val = f2bf((acc[i][j][r] + bv) * mult);
        if (seg < 2) lds[ml * 136 + nl] = val;   // [t][n] for Q/K
        else         lds[nl * 136 + ml] = val;   // [n][t] for V^T
      }
    }
  }
  __syncthreads();

  const int row = tid >> 1, half = tid & 1;
  const unsigned short* src = lds + row * 136 + half * 64;
  if (seg < 2) {
    const int m = m0 + row, b = m >> 12, t = m & (TSEQ - 1);
    const int nn = (n0 - seg * CDIM) + half * 64;   // multiple of 64
    const int h = nn >> 6;
    unsigned short* base = (seg == 0) ? qbuf : kbuf;
    unsigned short* dst = base + ((size_t)(b * NHEAD + h) * TSEQ + t) * 64;
#pragma unroll
    for (int k = 0; k < 8; ++k)
      *(uint4*)(dst + k * 8) = *(const uint4*)(src + k * 8);
  } else {
    const int nn = (n0 - 2 * CDIM) + row;
    const int h = nn >> 6, d = nn & 63;
    const int b = m0 >> 12, t0 = (m0 & (TSEQ - 1)) + half * 64;
    unsigned short* dst = vtbuf + ((size_t)(b * NHEAD + h) * 64 + d) * TSEQ + t0;
    // permuted store: dst chunk k holds keys {2(k>>2)}*16+(k&3)*4+0..3 then +16
#pragma unroll
    for (int k = 0; k < 8; ++k) {
      const int s0 = 32 * (k >> 2) + 4 * (k & 3);
      uint2 a = *(const uint2*)(src + s0);
      uint2 c = *(const uint2*)(src + s0 + 16);
      uint4 w = {a.x, a.y, c.x, c.y};
      *(uint4*)(dst + k * 8) = w;
    }
  }
}

// GEMM2: out = y@W_proj + b_proj (fp32 out)
__global__ __launch_bounds__(256, 4) void gemm_out_kernel(
    const unsigned short* __restrict__ A, const unsigned short* __restrict__ BTm,
    const float* __restrict__ bias, float* __restrict__ out) {
  __shared__ __align__(16) unsigned short lds[16384];   // 2-phase dbuf
  f32x4 zero = {0.f, 0.f, 0.f, 0.f};
  f32x4 acc[4][4];
#pragma unroll
  for (int i = 0; i < 4; ++i)
#pragma unroll
    for (int j = 0; j < 4; ++j) acc[i][j] = zero;

  const int m0 = blockIdx.y * 128, n0 = blockIdx.x * 128;
  gemm_bt_mainloop(A, BTm, CDIM, m0, n0, lds, acc);

  const int tid = threadIdx.x;
  const int wave = tid >> 6, lane = tid & 63;
  const int quad = lane >> 4, l16 = lane & 15;
  const int wm = (wave >> 1) * 64, wn = (wave & 1) * 64;

#pragma unroll
  for (int j = 0; j < 4; ++j) {
    int n = n0 + wn + j * 16 + l16;
    float bv = bias[n];
#pragma unroll
    for (int i = 0; i < 4; ++i) {
#pragma unroll
      for (int r = 0; r < 4; ++r) {
        int m = m0 + wm + i * 16 + quad * 4 + r;
        out[(size_t)m * CDIM + n] = acc[i][j][r] + bv;
      }
    }
  }
}

// ---------------- attention (R8 version verbatim) ----------------
// S^T: A=K (m=key=l16 within 16-group, k=d=quad*8+j), B=Q (n=q=l16).
// C: col=l16=q, row=quad*4+r=key -> P lane-local (16 values: keys 16i+quad*4+r).
// PV (16x16x32): A = permuted V^T from LDS — ONE 16B read per frag (k-slot quad*8+i*4+r
// carries key 16(2f+i)+quad*4+r, f=frag); B = pack2bf(s-regs) in matching order.
// O C: col=l16=q, row=quad*4+r=d (+16dt) -> per-row norm via quad shfl-reduce.

// 512 threads stage one 64x64 K tile + one 64x64 (permuted) V^T tile (16B/lane each).
__device__ __forceinline__ void stage_kv(const unsigned short* __restrict__ Kp,
                                         const unsigned short* __restrict__ Vp,
                                         int j0, unsigned short* kb, unsigned short* vb,
                                         int tid, int wave) {
  const int row = tid >> 3;                              // 0..63
  const int col = ((tid & 7) ^ (row & 7)) * 8;           // XOR swizzle (self-inverse)
  __builtin_amdgcn_global_load_lds((gas_ptr)(Kp + (size_t)(j0 + row) * 64 + col),
                                   (las_ptr)(kb + wave * 512), 16, 0, 0);
  __builtin_amdgcn_global_load_lds((gas_ptr)(Vp + (size_t)row * TSEQ + j0 + col),
                                   (las_ptr)(vb + wave * 512), 16, 0, 0);
}

__device__ __forceinline__ void qk_score(const bf16x8 kf[8], const bf16x8 qf[2], f32x4 s[4]) {
  f32x4 zero = {0.f, 0.f, 0.f, 0.f};
#pragma unroll
  for (int i = 0; i < 4; ++i)
    s[i] = mfma16(kf[2 * i + 1], qf[1], mfma16(kf[2 * i], qf[0], zero));
}

// exp2 + (diagonal) causal mask + lane-local partial row-sum; packs P into the two
// PV B-frags (k-slot order quad*8 + i*4 + r == permuted V^T storage order).
template <bool MASKED>
__device__ __forceinline__ void exp_pack(const f32x4 s[4], int j0, int qabs,
                                         int l16, int quad, float& lsum, bf16x8 pf[2]) {
  unsigned int w[8];
#pragma unroll
  for (int i = 0; i < 4; ++i) {
    float p[4];
#pragma unroll
    for (int r = 0; r < 4; ++r) {
      p[r] = __builtin_amdgcn_exp2f(s[i][r]);
      if (MASKED) {
        if (j0 + i * 16 + quad * 4 + r > qabs) p[r] = 0.f;
      }
      lsum += p[r];
    }
    w[2 * i]     = pack2bf(p[0], p[1]);
    w[2 * i + 1] = pack2bf(p[2], p[3]);
  }
  u32x4 lo = {w[0], w[1], w[2], w[3]};   // keys i=0,1 at k-slots quad*8 + 0..7
  u32x4 hi = {w[4], w[5], w[6], w[7]};   // keys i=2,3
  pf[0] = __builtin_bit_cast(bf16x8, lo);
  pf[1] = __builtin_bit_cast(bf16x8, hi);
}

// PV: 8 mfma16 off 8 conflict-free 16B v reads (frag0 block=quad, frag1 block=4+quad,
// de-swizzled by x7 = l16&7; rows d = dt*16+l16).
__device__ __forceinline__ void pv(const unsigned short* __restrict__ vb,
                                   int l16, int quad, int x7,
                                   const bf16x8 pf[2], f32x4 o[4]) {
#pragma unroll
  for (int dt = 0; dt < 4; ++dt) {
    const unsigned short* vr = vb + (dt * 16 + l16) * 64;
    bf16x8 v0 = *(const bf16x8*)(vr + ((quad ^ x7) * 8));
    bf16x8 v1 = *(const bf16x8*)(vr + (((4 + quad) ^ x7) * 8));
    o[dt] = mfma16(v1, pf[1], mfma16(v0, pf[0], o[dt]));
  }
}

__global__ __launch_bounds__(512, 6) void attn_kernel(const unsigned short* __restrict__ qbuf,
                                                      const unsigned short* __restrict__ kbuf,
                                                      const unsigned short* __restrict__ vtbuf,
                                                      unsigned short* __restrict__ y) {
  __shared__ __align__(16) unsigned short k_lds[2][64 * 64];      // 2 x 8KB
  __shared__ __align__(16) unsigned short v_lds[2][64 * 64];      // 2 x 8KB

  const int tid = threadIdx.x;
  const int wave = tid >> 6, lane = tid & 63;
  const int quad = lane >> 4, l16 = lane & 15;
  const int x7 = l16 & 7;

  const int bh = blockIdx.x % 24;
  const int p = blockIdx.x / 24;            // 0..31; p=0 (longest stream) dispatches first
  const bool isA = wave < 4;                // waves 0-3: q-tile p; waves 4-7: q-tile 63-p
  const int qtile = isA ? p : (63 - p);
  const int q0 = qtile * 64 + (wave & 3) * 16;

  const unsigned short* Qp = qbuf + (size_t)bh * TSEQ * 64;
  const unsigned short* Kp = kbuf + (size_t)bh * TSEQ * 64;
  const unsigned short* Vp = vtbuf + (size_t)bh * 64 * TSEQ;

  bf16x8 qf[2];
  qf[0] = *(const bf16x8*)(Qp + (size_t)(q0 + l16) * 64 + quad * 8);
  qf[1] = *(const bf16x8*)(Qp + (size_t)(q0 + l16) * 64 + 32 + quad * 8);

  f32x4 zero = {0.f, 0.f, 0.f, 0.f};
  f32x4 o[4];
#pragma unroll
  for (int dt = 0; dt < 4; ++dt) o[dt] = zero;
  float ls = 0.f;

  const int kcol0 = (quad ^ x7) * 8;          // swizzled K frag column (shorts)
  const int ntiles = 64 - p;                  // key tiles 0..63-p
  const int lasttile = isA ? p : (ntiles - 1);// this wave's diagonal tile (== qtile)

  stage_kv(Kp, Vp, 0, k_lds[0], v_lds[0], tid, wave);

  for (int jt = 0; jt < ntiles; ++jt) {
    __syncthreads();   // stage(jt) visible; other buffer free for restage
    if (jt + 1 < ntiles)
      stage_kv(Kp, Vp, (jt + 1) * 64, k_lds[(jt + 1) & 1], v_lds[(jt + 1) & 1], tid, wave);

    if (jt <= lasttile) {                    // wave-uniform; B-waves always active
      const unsigned short* kb = k_lds[jt & 1];
      const unsigned short* vb = v_lds[jt & 1];
      const int j0 = jt * 64;

      bf16x8 kf[8];
#pragma unroll
      for (int i = 0; i < 4; ++i) {
        kf[2 * i]     = *(const bf16x8*)(kb + (16 * i + l16) * 64 + kcol0);
        kf[2 * i + 1] = *(const bf16x8*)(kb + (16 * i + l16) * 64 + (kcol0 ^ 32));
      }

      f32x4 s[4];
      qk_score(kf, qf, s);

      bf16x8 pf[2];
      if (jt == lasttile) exp_pack<true>(s, j0, q0 + l16, l16, quad, ls, pf);
      else                exp_pack<false>(s, j0, q0 + l16, l16, quad, ls, pf);

      pv(vb, l16, quad, x7, pf, o);
    }
  }

  // full row-sum for q=l16: reduce partial sums across the 4 quads
  ls += __shfl_xor(ls, 16); ls += __shfl_xor(ls, 32);
  const float inv = 1.0f / ls;

  // O: col=l16=q (t = q0+l16), row = dt*16 + quad*4 + r = d
  const int b = bh / NHEAD, hd = bh - b * NHEAD;
  unsigned short* yr = y + (size_t)(b * TSEQ + q0 + l16) * CDIM + hd * 64 + quad * 4;
#pragma unroll
  for (int dt = 0; dt < 4; ++dt) {
    uint2 w;
    w.x = pack2bf(o[dt][0] * inv, o[dt][1] * inv);
    w.y = pack2bf(o[dt][2] * inv, o[dt][3] * inv);
    *(uint2*)(yr + dt * 16) = w;
  }
}

// ---------------- launch ----------------

extern "C" void kernel_launch(void* const* d_in, const int* in_sizes, int n_in,
                              void* d_out, int out_size, void* d_ws, size_t ws_size,
                              hipStream_t stream) {
  const float* x      = (const float*)d_in[0];
  const float* W_attn = (const float*)d_in[1];
  const float* b_attn = (const float*)d_in[2];
  const float* W_proj = (const float*)d_in[3];
  const float* b_proj = (const float*)d_in[4];
  float* out = (float*)d_out;

  unsigned short* xb    = (unsigned short*)d_ws;                  // [8192,768] bf16 (later reused as y)
  unsigned short* WaT   = xb + (size_t)BT_TOT * CDIM;             // [2304,768]
  unsigned short* WpT   = WaT + (size_t)C3 * CDIM;                // [768,768]
  unsigned short* qbuf  = WpT + (size_t)CDIM * CDIM;              // [24,4096,64]
  unsigned short* kbuf  = qbuf + (size_t)2 * NHEAD * TSEQ * 64;   // [24,4096,64]
  unsigned short* vtbuf = kbuf + (size_t)2 * NHEAD * TSEQ * 64;   // [24,64,4096] (key-permuted)
  unsigned short* ybuf  = xb;  // x dead after GEMM1

  prep_kernel<<<PREP_CAST_BLOCKS + PREP_WA_BLOCKS + PREP_WP_BLOCKS, 256, 0, stream>>>(
      x, xb, W_attn, WaT, W_proj, WpT);
  gemm_qkv_kernel<<<dim3(C3 / 128, BT_TOT / 128), 256, 0, stream>>>(xb, WaT, b_attn,
                                                                    qbuf, kbuf, vtbuf);
  attn_kernel<<<dim3(24 * 32), 512, 0, stream>>>(qbuf, kbuf, vtbuf, ybuf);
  gemm_out_kernel<<<dim3(CDIM / 128, BT_TOT / 128), 256, 0, stream>>>(ybuf, WpT, b_proj, out);
}

// Round 14
// 220.634 us; speedup vs baseline: 1.8695x; 1.0097x over previous
//
#include <hip/hip_runtime.h>

// Causal self-attention, B=2 T=4096 C=768 H=12 D=64, bf16 MFMA pipeline:
//   prep: ONE fused kernel (cast x->bf16; transpose W_attn/W_proj) — R13: -3us.
//   GEMM1 (x @ W_attn + b) -> Q[b,h,t,d], K[b,h,t,d] (pre-scaled by log2e/8),
//     V^T[b,h,d,t'] where t' is PER-64-TILE KEY-PERMUTED: key i*16+q4*4+r stored at
//     (i>>1)*32 + q4*8 + (i&1)*4 + r (feeds attention's in-register PV path).
//   GEMM mainloops: 3-buffer, ONE barrier/iter, vmcnt(4) — strictly dominates both
//     R8 (1 barrier but vmcnt(0) drain = zero latency cover) and R11 (2-iter cover
//     but 2 barriers; measured neutral vs R8 -> barrier cost ate the cover gain).
//     Per iter t: stage S(t+2)->buf[(t-1)%3] (consumed last iter), vmcnt(4)
//     guarantees S(t+1) landed in every wave before the single end-of-iter barrier,
//     so iter t+1's reads are safe with ONE FULL ITER of staging-latency cover.
//   attention: R8 version verbatim (70.4us, conflicts=0, ~87% of the 85B/cy LDS
//     ceiling at its geometry; R9 direct-K and R10 dual-chunk both refuted).
//   GEMM2 (y @ W_proj + b) -> out fp32

#define TSEQ   4096
#define NHEAD  12
#define CDIM   768
#define C3     2304
#define BT_TOT 8192   // B*T

typedef __bf16 bf16x8 __attribute__((ext_vector_type(8)));
typedef __bf16 bf16x2 __attribute__((ext_vector_type(2)));
typedef float  f32x4  __attribute__((ext_vector_type(4)));
typedef unsigned int u32x4 __attribute__((ext_vector_type(4)));

__device__ __forceinline__ unsigned short f2bf(float f) {
  unsigned int u = __builtin_bit_cast(unsigned int, f);
  u += 0x7FFFu + ((u >> 16) & 1u);            // round-to-nearest-even
  return (unsigned short)(u >> 16);
}

// native gfx950 f32->bf16 (v_cvt_pk_bf16_f32) — 1 instr per pair
__device__ __forceinline__ unsigned int pack2bf(float a, float b) {
  bf16x2 v = {(__bf16)a, (__bf16)b};
  return __builtin_bit_cast(unsigned int, v);
}

__device__ __forceinline__ f32x4 mfma16(bf16x8 a, bf16x8 b, f32x4 c) {
  return __builtin_amdgcn_mfma_f32_16x16x32_bf16(a, b, c, 0, 0, 0);
}

typedef const __attribute__((address_space(1))) void* gas_ptr;
typedef __attribute__((address_space(3))) void* las_ptr;

// s_waitcnt masks: bits[3:0]=vmcnt[3:0], [6:4]=expcnt, [13:8]=lgkmcnt, [15:14]=vmcnt[5:4]
#define WAIT_VM4() __builtin_amdgcn_s_waitcnt(0x3F74)   // vmcnt<=4, lgkm/exp free
#define WAIT_VM0() __builtin_amdgcn_s_waitcnt(0x3F70)   // vmcnt<=0
#define SBAR()     __builtin_amdgcn_sched_barrier(0)

// ---------------- fused prologue ----------------
// blocks [0,6144): cast x (4 f32/thread); [6144,7872): W_attn^T; [7872,8448): W_proj^T.

#define PREP_CAST_BLOCKS  6144   // 8192*768 / (256*4)
#define PREP_WA_BLOCKS    1728   // (2304/32)*(768/32)
#define PREP_WP_BLOCKS     576   // (768/32)*(768/32)

__global__ __launch_bounds__(256) void prep_kernel(
    const float* __restrict__ x, unsigned short* __restrict__ xb,
    const float* __restrict__ W_attn, unsigned short* __restrict__ WaT,
    const float* __restrict__ W_proj, unsigned short* __restrict__ WpT) {
  const int bk = blockIdx.x;
  if (bk < PREP_CAST_BLOCKS) {
    int i = (bk * 256 + threadIdx.x) * 4;
    float4 v = *(const float4*)(x + i);
    ushort4 u;
    u.x = f2bf(v.x); u.y = f2bf(v.y); u.z = f2bf(v.z); u.w = f2bf(v.w);
    *(ushort4*)(xb + i) = u;
    return;
  }
  __shared__ float tile[32][33];
  const float* src;
  unsigned short* dst;
  int K, N, n0, k0;
  if (bk < PREP_CAST_BLOCKS + PREP_WA_BLOCKS) {
    const int j = bk - PREP_CAST_BLOCKS;
    src = W_attn; dst = WaT; K = CDIM; N = C3;
    n0 = (j % 72) * 32; k0 = (j / 72) * 32;
  } else {
    const int j = bk - (PREP_CAST_BLOCKS + PREP_WA_BLOCKS);
    src = W_proj; dst = WpT; K = CDIM; N = CDIM;
    n0 = (j % 24) * 32; k0 = (j / 24) * 32;
  }
  const int tx = threadIdx.x & 31, ty = threadIdx.x >> 5;  // 32 x 8
#pragma unroll
  for (int i = 0; i < 4; ++i)
    tile[ty + i * 8][tx] = src[(size_t)(k0 + ty + i * 8) * N + n0 + tx];
  __syncthreads();
#pragma unroll
  for (int i = 0; i < 4; ++i)
    dst[(size_t)(n0 + ty + i * 8) * K + k0 + tx] = f2bf(tile[tx][ty + i * 8]);
}

// ---------------- GEMM core (C = A[M,K] * BT[N,K]^T), 128x128 tile, BK=32 ----------------
// 3-buffer, one barrier per iter, vmcnt(4): buf b (shorts) at b*8192 + {A:0..4095, B:4096..8191}.

__device__ __forceinline__ void stage_gemm(const unsigned short* __restrict__ A,
                                           const unsigned short* __restrict__ BTm,
                                           int K, int m0, int n0, int k0,
                                           unsigned short* buf, int wave,
                                           int srow, int scol) {
#pragma unroll
  for (int r = 0; r < 2; ++r) {
    const unsigned short* ga = A + (size_t)(m0 + r * 64 + srow) * K + k0 + scol;
    __builtin_amdgcn_global_load_lds((gas_ptr)ga,
        (las_ptr)(buf + r * 2048 + wave * 512), 16, 0, 0);
    const unsigned short* gb = BTm + (size_t)(n0 + r * 64 + srow) * K + k0 + scol;
    __builtin_amdgcn_global_load_lds((gas_ptr)gb,
        (las_ptr)(buf + 4096 + r * 2048 + wave * 512), 16, 0, 0);
  }
}

__device__ __forceinline__ void gemm_bt_mainloop(const unsigned short* __restrict__ A,
                                                 const unsigned short* __restrict__ BTm,
                                                 int K, int m0, int n0,
                                                 unsigned short* lds, f32x4 acc[4][4]) {
  const int tid = threadIdx.x;
  const int wave = tid >> 6, lane = tid & 63;
  const int quad = lane >> 4, l16 = lane & 15;
  const int wm = (wave >> 1) * 64, wn = (wave & 1) * 64;
  const int srow = tid >> 2;          // 0..63
  const int scol = (tid & 3) * 8;     // shorts

  const int nt = K / 32;              // 24 for K=768 (needs nt >= 3)
  stage_gemm(A, BTm, K, m0, n0, 0,  lds,        wave, srow, scol);   // S0 -> buf0
  stage_gemm(A, BTm, K, m0, n0, 32, lds + 8192, wave, srow, scol);   // S1 -> buf1
  WAIT_VM4();                         // S0 landed (only S1's 4 loads in flight)
  SBAR();
  __builtin_amdgcn_s_barrier();       // entry barrier of iter 0: all waves' S0 landed
  SBAR();

  for (int t = 0; t < nt; ++t) {
    if (t + 2 < nt) {
      // stage S(t+2) into buf[(t+2)%3] == buf[(t-1)%3], consumed last iter by all waves
      stage_gemm(A, BTm, K, m0, n0, (t + 2) * 32, lds + ((t + 2) % 3) * 8192,
                 wave, srow, scol);
      WAIT_VM4();                     // S(t+1) landed; S(t+2) stays in flight (1-iter cover)
    } else {
      WAIT_VM0();                     // tail drain
    }
    SBAR();

    const unsigned short* buf = lds + (t % 3) * 8192;
    bf16x8 af[4], bfr[4];
#pragma unroll
    for (int i = 0; i < 4; ++i) {
      af[i]  = *(const bf16x8*)(buf + (wm + i * 16 + l16) * 32 + quad * 8);
      bfr[i] = *(const bf16x8*)(buf + 4096 + (wn + i * 16 + l16) * 32 + quad * 8);
    }
#pragma unroll
    for (int i = 0; i < 4; ++i)
#pragma unroll
      for (int j = 0; j < 4; ++j)
        acc[i][j] = mfma16(af[i], bfr[j], acc[i][j]);

    if (t + 1 < nt) {
      SBAR();
      __builtin_amdgcn_s_barrier();   // single barrier: entry of iter t+1
      SBAR();
    }
  }
  __syncthreads();                    // full drain + sync before epilogue LDS reuse
}

// GEMM1: qkv = x@W_attn + b_attn -> Q/K (b,h,t,d) and key-permuted V^T (b,h,d,t'), bf16.
// K pre-scaled by log2e/8. Epilogue: tile -> LDS (transposed for V), then coalesced
// 16B stores; the V path gathers 2x8B per 16B chunk to apply the per-64 key permutation
// col'(key) = (key>>5)*32 + ((key>>2)&3)*8 + ((key>>4)&1)*4 + (key&3).
__global__ __launch_bounds__(256, 3) void gemm_qkv_kernel(
    const unsigned short* __restrict__ A, const unsigned short* __restrict__ BTm,
    const float* __restrict__ bias,
    unsigned short* __restrict__ qbuf, unsigned short* __restrict__ kbuf,
    unsigned short* __restrict__ vtbuf) {
  __shared__ __align__(16) unsigned short lds[3 * 8192];  // 48KB pipeline; epilogue reuses 34KB
  f32x4 zero = {0.f, 0.f, 0.f, 0.f};
  f32x4 acc[4][4];
#pragma unroll
  for (int i = 0; i < 4; ++i)
#pragma unroll
    for (int j = 0; j < 4; ++j) acc[i][j] = zero;

  const int m0 = blockIdx.y * 128, n0 = blockIdx.x * 128;
  gemm_bt_mainloop(A, BTm, CDIM, m0, n0, lds, acc);
  // mainloop's final __syncthreads: all waves synced, LDS reusable

  const int tid = threadIdx.x;
  const int wave = tid >> 6, lane = tid & 63;
  const int quad = lane >> 4, l16 = lane & 15;
  const int wm = (wave >> 1) * 64, wn = (wave & 1) * 64;
  const float KSCALE = 0.125f * 1.44269504088896340736f;  // 1/sqrt(64) * log2(e)

  const int seg = n0 / CDIM;   // 0=Q 1=K 2=V — uniform per block (128 | 768)
  const float mult = (seg == 1) ? KSCALE : 1.0f;

#pragma unroll
  for (int j = 0; j < 4; ++j) {
    const int nl = wn + j * 16 + l16;
    const float bv = bias[n0 + nl];
#pragma unroll
    for (int i = 0; i < 4; ++i) {
#pragma unroll
      for (int r = 0; r < 4; ++r) {
        const int ml = wm + i * 16 + quad * 4 + r;
        unsigned short val = f2bf((acc[i][j][r] + bv) * mult);
        if (seg < 2) lds[ml * 136 + nl] = val;   // [t][n] for Q/K
        else         lds[nl * 136 + ml] = val;   // [n][t] for V^T
      }
    }
  }
  __syncthreads();

  const int row = tid >> 1, half = tid & 1;
  const unsigned short* src = lds + row * 136 + half * 64;
  if (seg < 2) {
    const int m = m0 + row, b = m >> 12, t = m & (TSEQ - 1);
    const int nn = (n0 - seg * CDIM) + half * 64;   // multiple of 64
    const int h = nn >> 6;
    unsigned short* base = (seg == 0) ? qbuf : kbuf;
    unsigned short* dst = base + ((size_t)(b * NHEAD + h) * TSEQ + t) * 64;
#pragma unroll
    for (int k = 0; k < 8; ++k)
      *(uint4*)(dst + k * 8) = *(const uint4*)(src + k * 8);
  } else {
    const int nn = (n0 - 2 * CDIM) + row;
    const int h = nn >> 6, d = nn & 63;
    const int b = m0 >> 12, t0 = (m0 & (TSEQ - 1)) + half * 64;
    unsigned short* dst = vtbuf + ((size_t)(b * NHEAD + h) * 64 + d) * TSEQ + t0;
    // permuted store: dst chunk k holds keys {2(k>>2)}*16+(k&3)*4+0..3 then +16
#pragma unroll
    for (int k = 0; k < 8; ++k) {
      const int s0 = 32 * (k >> 2) + 4 * (k & 3);
      uint2 a = *(const uint2*)(src + s0);
      uint2 c = *(const uint2*)(src + s0 + 16);
      uint4 w = {a.x, a.y, c.x, c.y};
      *(uint4*)(dst + k * 8) = w;
    }
  }
}

// GEMM2: out = y@W_proj + b_proj (fp32 out)
__global__ __launch_bounds__(256, 3) void gemm_out_kernel(
    const unsigned short* __restrict__ A, const unsigned short* __restrict__ BTm,
    const float* __restrict__ bias, float* __restrict__ out) {
  __shared__ __align__(16) unsigned short lds[3 * 8192];   // 48KB pipeline
  f32x4 zero = {0.f, 0.f, 0.f, 0.f};
  f32x4 acc[4][4];
#pragma unroll
  for (int i = 0; i < 4; ++i)
#pragma unroll
    for (int j = 0; j < 4; ++j) acc[i][j] = zero;

  const int m0 = blockIdx.y * 128, n0 = blockIdx.x * 128;
  gemm_bt_mainloop(A, BTm, CDIM, m0, n0, lds, acc);

  const int tid = threadIdx.x;
  const int wave = tid >> 6, lane = tid & 63;
  const int quad = lane >> 4, l16 = lane & 15;
  const int wm = (wave >> 1) * 64, wn = (wave & 1) * 64;

#pragma unroll
  for (int j = 0; j < 4; ++j) {
    int n = n0 + wn + j * 16 + l16;
    float bv = bias[n];
#pragma unroll
    for (int i = 0; i < 4; ++i) {
#pragma unroll
      for (int r = 0; r < 4; ++r) {
        int m = m0 + wm + i * 16 + quad * 4 + r;
        out[(size_t)m * CDIM + n] = acc[i][j][r] + bv;
      }
    }
  }
}

// ---------------- attention (R8 version verbatim) ----------------
// S^T: A=K (m=key=l16 within 16-group, k=d=quad*8+j), B=Q (n=q=l16).
// C: col=l16=q, row=quad*4+r=key -> P lane-local (16 values: keys 16i+quad*4+r).
// PV (16x16x32): A = permuted V^T from LDS — ONE 16B read per frag (k-slot quad*8+i*4+r
// carries key 16(2f+i)+quad*4+r, f=frag); B = pack2bf(s-regs) in matching order.
// O C: col=l16=q, row=quad*4+r=d (+16dt) -> per-row norm via quad shfl-reduce.

// 512 threads stage one 64x64 K tile + one 64x64 (permuted) V^T tile (16B/lane each).
__device__ __forceinline__ void stage_kv(const unsigned short* __restrict__ Kp,
                                         const unsigned short* __restrict__ Vp,
                                         int j0, unsigned short* kb, unsigned short* vb,
                                         int tid, int wave) {
  const int row = tid >> 3;                              // 0..63
  const int col = ((tid & 7) ^ (row & 7)) * 8;           // XOR swizzle (self-inverse)
  __builtin_amdgcn_global_load_lds((gas_ptr)(Kp + (size_t)(j0 + row) * 64 + col),
                                   (las_ptr)(kb + wave * 512), 16, 0, 0);
  __builtin_amdgcn_global_load_lds((gas_ptr)(Vp + (size_t)row * TSEQ + j0 + col),
                                   (las_ptr)(vb + wave * 512), 16, 0, 0);
}

__device__ __forceinline__ void qk_score(const bf16x8 kf[8], const bf16x8 qf[2], f32x4 s[4]) {
  f32x4 zero = {0.f, 0.f, 0.f, 0.f};
#pragma unroll
  for (int i = 0; i < 4; ++i)
    s[i] = mfma16(kf[2 * i + 1], qf[1], mfma16(kf[2 * i], qf[0], zero));
}

// exp2 + (diagonal) causal mask + lane-local partial row-sum; packs P into the two
// PV B-frags (k-slot order quad*8 + i*4 + r == permuted V^T storage order).
template <bool MASKED>
__device__ __forceinline__ void exp_pack(const f32x4 s[4], int j0, int qabs,
                                         int l16, int quad, float& lsum, bf16x8 pf[2]) {
  unsigned int w[8];
#pragma unroll
  for (int i = 0; i < 4; ++i) {
    float p[4];
#pragma unroll
    for (int r = 0; r < 4; ++r) {
      p[r] = __builtin_amdgcn_exp2f(s[i][r]);
      if (MASKED) {
        if (j0 + i * 16 + quad * 4 + r > qabs) p[r] = 0.f;
      }
      lsum += p[r];
    }
    w[2 * i]     = pack2bf(p[0], p[1]);
    w[2 * i + 1] = pack2bf(p[2], p[3]);
  }
  u32x4 lo = {w[0], w[1], w[2], w[3]};   // keys i=0,1 at k-slots quad*8 + 0..7
  u32x4 hi = {w[4], w[5], w[6], w[7]};   // keys i=2,3
  pf[0] = __builtin_bit_cast(bf16x8, lo);
  pf[1] = __builtin_bit_cast(bf16x8, hi);
}

// PV: 8 mfma16 off 8 conflict-free 16B v reads (frag0 block=quad, frag1 block=4+quad,
// de-swizzled by x7 = l16&7; rows d = dt*16+l16).
__device__ __forceinline__ void pv(const unsigned short* __restrict__ vb,
                                   int l16, int quad, int x7,
                                   const bf16x8 pf[2], f32x4 o[4]) {
#pragma unroll
  for (int dt = 0; dt < 4; ++dt) {
    const unsigned short* vr = vb + (dt * 16 + l16) * 64;
    bf16x8 v0 = *(const bf16x8*)(vr + ((quad ^ x7) * 8));
    bf16x8 v1 = *(const bf16x8*)(vr + (((4 + quad) ^ x7) * 8));
    o[dt] = mfma16(v1, pf[1], mfma16(v0, pf[0], o[dt]));
  }
}

__global__ __launch_bounds__(512, 6) void attn_kernel(const unsigned short* __restrict__ qbuf,
                                                      const unsigned short* __restrict__ kbuf,
                                                      const unsigned short* __restrict__ vtbuf,
                                                      unsigned short* __restrict__ y) {
  __shared__ __align__(16) unsigned short k_lds[2][64 * 64];      // 2 x 8KB
  __shared__ __align__(16) unsigned short v_lds[2][64 * 64];      // 2 x 8KB

  const int tid = threadIdx.x;
  const int wave = tid >> 6, lane = tid & 63;
  const int quad = lane >> 4, l16 = lane & 15;
  const int x7 = l16 & 7;

  const int bh = blockIdx.x % 24;
  const int p = blockIdx.x / 24;            // 0..31; p=0 (longest stream) dispatches first
  const bool isA = wave < 4;                // waves 0-3: q-tile p; waves 4-7: q-tile 63-p
  const int qtile = isA ? p : (63 - p);
  const int q0 = qtile * 64 + (wave & 3) * 16;

  const unsigned short* Qp = qbuf + (size_t)bh * TSEQ * 64;
  const unsigned short* Kp = kbuf + (size_t)bh * TSEQ * 64;
  const unsigned short* Vp = vtbuf + (size_t)bh * 64 * TSEQ;

  bf16x8 qf[2];
  qf[0] = *(const bf16x8*)(Qp + (size_t)(q0 + l16) * 64 + quad * 8);
  qf[1] = *(const bf16x8*)(Qp + (size_t)(q0 + l16) * 64 + 32 + quad * 8);

  f32x4 zero = {0.f, 0.f, 0.f, 0.f};
  f32x4 o[4];
#pragma unroll
  for (int dt = 0; dt < 4; ++dt) o[dt] = zero;
  float ls = 0.f;

  const int kcol0 = (quad ^ x7) * 8;          // swizzled K frag column (shorts)
  const int ntiles = 64 - p;                  // key tiles 0..63-p
  const int lasttile = isA ? p : (ntiles - 1);// this wave's diagonal tile (== qtile)

  stage_kv(Kp, Vp, 0, k_lds[0], v_lds[0], tid, wave);

  for (int jt = 0; jt < ntiles; ++jt) {
    __syncthreads();   // stage(jt) visible; other buffer free for restage
    if (jt + 1 < ntiles)
      stage_kv(Kp, Vp, (jt + 1) * 64, k_lds[(jt + 1) & 1], v_lds[(jt + 1) & 1], tid, wave);

    if (jt <= lasttile) {                    // wave-uniform; B-waves always active
      const unsigned short* kb = k_lds[jt & 1];
      const unsigned short* vb = v_lds[jt & 1];
      const int j0 = jt * 64;

      bf16x8 kf[8];
#pragma unroll
      for (int i = 0; i < 4; ++i) {
        kf[2 * i]     = *(const bf16x8*)(kb + (16 * i + l16) * 64 + kcol0);
        kf[2 * i + 1] = *(const bf16x8*)(kb + (16 * i + l16) * 64 + (kcol0 ^ 32));
      }

      f32x4 s[4];
      qk_score(kf, qf, s);

      bf16x8 pf[2];
      if (jt == lasttile) exp_pack<true>(s, j0, q0 + l16, l16, quad, ls, pf);
      else                exp_pack<false>(s, j0, q0 + l16, l16, quad, ls, pf);

      pv(vb, l16, quad, x7, pf, o);
    }
  }

  // full row-sum for q=l16: reduce partial sums across the 4 quads
  ls += __shfl_xor(ls, 16); ls += __shfl_xor(ls, 32);
  const float inv = 1.0f / ls;

  // O: col=l16=q (t = q0+l16), row = dt*16 + quad*4 + r = d
  const int b = bh / NHEAD, hd = bh - b * NHEAD;
  unsigned short* yr = y + (size_t)(b * TSEQ + q0 + l16) * CDIM + hd * 64 + quad * 4;
#pragma unroll
  for (int dt = 0; dt < 4; ++dt) {
    uint2 w;
    w.x = pack2bf(o[dt][0] * inv, o[dt][1] * inv);
    w.y = pack2bf(o[dt][2] * inv, o[dt][3] * inv);
    *(uint2*)(yr + dt * 16) = w;
  }
}

// ---------------- launch ----------------

extern "C" void kernel_launch(void* const* d_in, const int* in_sizes, int n_in,
                              void* d_out, int out_size, void* d_ws, size_t ws_size,
                              hipStream_t stream) {
  const float* x      = (const float*)d_in[0];
  const float* W_attn = (const float*)d_in[1];
  const float* b_attn = (const float*)d_in[2];
  const float* W_proj = (const float*)d_in[3];
  const float* b_proj = (const float*)d_in[4];
  float* out = (float*)d_out;

  unsigned short* xb    = (unsigned short*)d_ws;                  // [8192,768] bf16 (later reused as y)
  unsigned short* WaT   = xb + (size_t)BT_TOT * CDIM;             // [2304,768]
  unsigned short* WpT   = WaT + (size_t)C3 * CDIM;                // [768,768]
  unsigned short* qbuf  = WpT + (size_t)CDIM * CDIM;              // [24,4096,64]
  unsigned short* kbuf  = qbuf + (size_t)2 * NHEAD * TSEQ * 64;   // [24,4096,64]
  unsigned short* vtbuf = kbuf + (size_t)2 * NHEAD * TSEQ * 64;   // [24,64,4096] (key-permuted)
  unsigned short* ybuf  = xb;  // x dead after GEMM1

  prep_kernel<<<PREP_CAST_BLOCKS + PREP_WA_BLOCKS + PREP_WP_BLOCKS, 256, 0, stream>>>(
      x, xb, W_attn, WaT, W_proj, WpT);
  gemm_qkv_kernel<<<dim3(C3 / 128, BT_TOT / 128), 256, 0, stream>>>(xb, WaT, b_attn,
                                                                    qbuf, kbuf, vtbuf);
  attn_kernel<<<dim3(24 * 32), 512, 0, stream>>>(qbuf, kbuf, vtbuf, ybuf);
  gemm_out_kernel<<<dim3(CDIM / 128, BT_TOT / 128), 256, 0, stream>>>(ybuf, WpT, b_proj, out);
}